// Round 4
// baseline (591.082 us; speedup 1.0000x reference)
//
#include <hip/hip_runtime.h>
#include <hip/hip_bf16.h>
#include <cstdint>
#include <cstddef>

#define N_NODES 50000
#define N_EDGES 800000
#define FIN 512
#define HW_ 128
#define NCLS 16
#define SCAN_NB 196  // ceil(50000/256)

typedef __attribute__((ext_vector_type(4))) float floatx4;
typedef __attribute__((ext_vector_type(4))) int int4v;
typedef __bf16 bf16x8 __attribute__((ext_vector_type(8)));

__device__ __forceinline__ void glds16(const __bf16* g, __bf16* l) {
  __builtin_amdgcn_global_load_lds(
      (const __attribute__((address_space(1))) void*)g,
      (__attribute__((address_space(3))) void*)l, 16, 0, 0);
}

// ---------------- CSR build: histogram ----------------
__global__ void k_hist(const int* __restrict__ idx, int* __restrict__ cnt) {
  int e = blockIdx.x * blockDim.x + threadIdx.x;
  if (e < N_EDGES) atomicAdd(&cnt[idx[e]], 1);
}

// ---------------- parallel scan: per-block sums ----------------
__global__ __launch_bounds__(256) void k_scan_block(const int* __restrict__ cnt,
                                                    int* __restrict__ bsum) {
  int t = blockIdx.x * 256 + threadIdx.x;
  int v = (t < N_NODES) ? cnt[t] : 0;
#pragma unroll
  for (int o = 32; o >= 1; o >>= 1) v += __shfl_down(v, o);
  __shared__ int ws[4];
  if ((threadIdx.x & 63) == 0) ws[threadIdx.x >> 6] = v;
  __syncthreads();
  if (threadIdx.x == 0) bsum[blockIdx.x] = ws[0] + ws[1] + ws[2] + ws[3];
}

// ---------------- parallel scan: top-level exclusive scan ----------------
__global__ __launch_bounds__(256) void k_scan_top(const int* __restrict__ bsum,
                                                  int* __restrict__ bsumex) {
  int t = threadIdx.x;
  int lane = t & 63;
  int orig = (t < SCAN_NB) ? bsum[t] : 0;
  int v = orig;
#pragma unroll
  for (int o = 1; o < 64; o <<= 1) {
    int n = __shfl_up(v, o);
    if (lane >= o) v += n;
  }
  __shared__ int wt[4];
  if (lane == 63) wt[t >> 6] = v;
  __syncthreads();
  int add = 0;
  for (int w = 0; w < (t >> 6); w++) add += wt[w];
  if (t < SCAN_NB) bsumex[t] = v + add - orig;
}

// ---------------- parallel scan: fill rowptr + wcur ----------------
__global__ __launch_bounds__(256) void k_scan_fill(const int* __restrict__ cnt,
                                                   const int* __restrict__ bsumex,
                                                   int* __restrict__ rowptr,
                                                   int* __restrict__ wcur) {
  int t = blockIdx.x * 256 + threadIdx.x;
  int lane = threadIdx.x & 63;
  int c = (t < N_NODES) ? cnt[t] : 0;
  int v = c;
#pragma unroll
  for (int o = 1; o < 64; o <<= 1) {
    int n = __shfl_up(v, o);
    if (lane >= o) v += n;
  }
  __shared__ int wt[4];
  if (lane == 63) wt[threadIdx.x >> 6] = v;
  __syncthreads();
  int add = bsumex[blockIdx.x];
  for (int w = 0; w < (threadIdx.x >> 6); w++) add += wt[w];
  int ex = v - c + add;
  if (t < N_NODES) { rowptr[t] = ex; wcur[t] = ex; }
  if (t == 0) rowptr[N_NODES] = N_EDGES;
}

// ---------------- scatter edges (packed col+val) ----------------
__global__ void k_scatter(const int* __restrict__ idx, const float* __restrict__ vals,
                          int* __restrict__ wcur, int2* __restrict__ epack) {
  int e = blockIdx.x * blockDim.x + threadIdx.x;
  if (e < N_EDGES) {
    int r = idx[e];
    int c = idx[N_EDGES + e];
    int p = atomicAdd(&wcur[r], 1);
    epack[p] = make_int2(c, __float_as_int(vals[e]));
  }
}

// ---------------- x: fp32 -> bf16 ----------------
__global__ __launch_bounds__(256) void k_xcast(const float* __restrict__ in,
                                               __bf16* __restrict__ out, int n8) {
  int t = blockIdx.x * 256 + threadIdx.x;
  if (t >= n8) return;
  floatx4 a = *(const floatx4*)(in + (size_t)t * 8);
  floatx4 b = *(const floatx4*)(in + (size_t)t * 8 + 4);
  union { bf16x8 v; int4v i; } u;
#pragma unroll
  for (int q = 0; q < 4; q++) { u.v[q] = (__bf16)a[q]; u.v[q + 4] = (__bf16)b[q]; }
  *(int4v*)(out + (size_t)t * 8) = u.i;
}

// ---------------- weight transpose + bf16 convert: [3][K][128] -> [3][128][K]
__global__ void k_wt(const float* __restrict__ in, __bf16* __restrict__ out, int K) {
  int t = blockIdx.x * 256 + threadIdx.x;
  int tot = 3 * K * 128;
  if (t >= tot) return;
  int i = t / (K * 128);
  int r = t - i * K * 128;
  int k = r >> 7;
  int nn = r & 127;
  out[(size_t)i * 128 * K + (size_t)nn * K + k] = (__bf16)in[t];
}

// ---------------- SpMM: one wave/row; 16 lanes x b128; 8 gathers in flight ---
template <bool OUTF32>
__global__ __launch_bounds__(256) void spmm_csr(
    const int* __restrict__ rowptr, const int2* __restrict__ epack,
    const __bf16* __restrict__ in,
    void* __restrict__ outp, int ostride) {
  int row = (int)((blockIdx.x * (size_t)blockDim.x + threadIdx.x) >> 6);
  if (row >= N_NODES) return;
  int lane = threadIdx.x & 63;
  int g = lane >> 4, l = lane & 15;
  int s = rowptr[row], e = rowptr[row + 1];
  float a[8] = {0.f, 0.f, 0.f, 0.f, 0.f, 0.f, 0.f, 0.f};
  int i = s + g;
  for (; i + 4 < e; i += 8) {
    int2 e0 = epack[i];
    int2 e1 = epack[i + 4];
    bf16x8 p0 = *(const bf16x8*)(in + ((size_t)e0.x << 7) + 8 * l);
    bf16x8 p1 = *(const bf16x8*)(in + ((size_t)e1.x << 7) + 8 * l);
    float v0 = __int_as_float(e0.y), v1 = __int_as_float(e1.y);
#pragma unroll
    for (int u = 0; u < 8; u++) a[u] += v0 * (float)p0[u] + v1 * (float)p1[u];
  }
  for (; i < e; i += 4) {
    int2 e0 = epack[i];
    bf16x8 p0 = *(const bf16x8*)(in + ((size_t)e0.x << 7) + 8 * l);
    float v0 = __int_as_float(e0.y);
#pragma unroll
    for (int u = 0; u < 8; u++) a[u] += v0 * (float)p0[u];
  }
#pragma unroll
  for (int u = 0; u < 8; u++) {
    a[u] += __shfl_xor(a[u], 16);
    a[u] += __shfl_xor(a[u], 32);
  }
  if (g == 0) {
    if (OUTF32) {
      float* o = (float*)outp + (size_t)row * ostride + 8 * l;
      *(floatx4*)o = floatx4{a[0], a[1], a[2], a[3]};
      *(floatx4*)(o + 4) = floatx4{a[4], a[5], a[6], a[7]};
    } else {
      union { bf16x8 v; int4v i; } u;
#pragma unroll
      for (int q = 0; q < 8; q++) u.v[q] = (__bf16)a[q];
      *(int4v*)((__bf16*)outp + (size_t)row * ostride + 8 * l) = u.i;
    }
  }
}

// ---------------- MFMA bf16 GEMM, 128x128 tile, global_load_lds staging ------
// C[M,384] = act(A[M,K] @ W + bias). A bf16 [M][K]; W transposed Bt[3][128][K].
template <bool HASB, bool O0F32>
__global__ __launch_bounds__(256) void gemm_mfma(
    const __bf16* __restrict__ Ab, int M, int K,
    const __bf16* __restrict__ Bt,
    const float* __restrict__ bias,
    void* __restrict__ out0, int s0,
    __bf16* __restrict__ out1, int s1,
    __bf16* __restrict__ out2, int s2) {
  __shared__ __align__(16) __bf16 sA[128 * 32];
  __shared__ __align__(16) __bf16 sB[128 * 32];
  int tid = threadIdx.x;
  int m0 = blockIdx.x * 128;
  int blk = blockIdx.y;
  const __bf16* Bblk = Bt + (size_t)blk * 128 * K;
  int wave = tid >> 6, lane = tid & 63;
  int wm = (wave & 1) * 64, wn = (wave >> 1) * 64;
  floatx4 acc[4][4] = {};

  // staging addressing: lane covers row r = wave*32 + inst*16 + (lane>>2),
  // lds slot lane&3; global chunk XOR-swizzled by row&3 (lane-constant).
  int rA = lane >> 2;
  int gch = (lane & 3) ^ (rA & 3);
  int r0 = wave * 32 + rA;
  int r1 = r0 + 16;
  int gm0 = m0 + r0; gm0 = (gm0 < M) ? gm0 : (M - 1);
  int gm1 = m0 + r1; gm1 = (gm1 < M) ? gm1 : (M - 1);
  const __bf16* pa0 = Ab + (size_t)gm0 * K + gch * 8;
  const __bf16* pa1 = Ab + (size_t)gm1 * K + gch * 8;
  const __bf16* pb0 = Bblk + (size_t)r0 * K + gch * 8;
  const __bf16* pb1 = Bblk + (size_t)r1 * K + gch * 8;
  __bf16* lA0 = sA + wave * 1024;
  __bf16* lA1 = sA + wave * 1024 + 512;
  __bf16* lB0 = sB + wave * 1024;
  __bf16* lB1 = sB + wave * 1024 + 512;

  // fragment addressing (swizzle-aware, lane-constant slot)
  int fm = lane & 15, fg = lane >> 4;
  int sloto = (fg ^ (fm & 3)) * 8;

  for (int k0 = 0; k0 < K; k0 += 32) {
    __syncthreads();   // prior iter's ds_reads done before overwrite
    glds16(pa0 + k0, lA0);
    glds16(pa1 + k0, lA1);
    glds16(pb0 + k0, lB0);
    glds16(pb1 + k0, lB1);
    __syncthreads();   // drains vmcnt (global_load_lds) for all waves

    bf16x8 af[4], bfr[4];
#pragma unroll
    for (int mt = 0; mt < 4; mt++)
      af[mt] = *(const bf16x8*)(sA + (wm + mt * 16 + fm) * 32 + sloto);
#pragma unroll
    for (int nt = 0; nt < 4; nt++)
      bfr[nt] = *(const bf16x8*)(sB + (wn + nt * 16 + fm) * 32 + sloto);
#pragma unroll
    for (int mt = 0; mt < 4; mt++)
#pragma unroll
      for (int nt = 0; nt < 4; nt++)
        acc[mt][nt] = __builtin_amdgcn_mfma_f32_16x16x32_bf16(af[mt], bfr[nt], acc[mt][nt], 0, 0, 0);
  }

  // epilogue: C/D layout col=lane&15, row=quad*4+reg (m89-verified)
  int colb = lane & 15, rbase = (lane >> 4) << 2;
  const float* bp = HASB ? (bias + blk * 128) : nullptr;
#pragma unroll
  for (int mt = 0; mt < 4; mt++)
#pragma unroll
    for (int r = 0; r < 4; r++) {
      int gm = m0 + wm + mt * 16 + rbase + r;
      if (gm >= M) continue;
#pragma unroll
      for (int nt = 0; nt < 4; nt++) {
        int gc = wn + nt * 16 + colb;
        float vv = acc[mt][nt][r];
        if (HASB) { vv += bp[gc]; vv = fmaxf(vv, 0.f); }
        if (blk == 0) {
          if (O0F32) ((float*)out0)[(size_t)gm * s0 + gc] = vv;
          else       ((__bf16*)out0)[(size_t)gm * s0 + gc] = (__bf16)vv;
        } else if (blk == 1) {
          out1[(size_t)gm * s1 + gc] = (__bf16)vv;
        } else {
          out2[(size_t)gm * s2 + gc] = (__bf16)vv;
        }
      }
    }
}

// ---------------- constc[c] = bf[c] + sum_k b2[k] * wf[k][c] ----------------
__global__ void k_const(const float* __restrict__ b2, const float* __restrict__ wf,
                        const float* __restrict__ bf, float* __restrict__ constc) {
  int c = threadIdx.x;
  if (c >= NCLS) return;
  float s = bf[c];
  for (int k = 0; k < 384; k++) s += b2[k] * wf[k * NCLS + c];
  constc[c] = s;
}

// ---------------- final: logits = concat(f0,f1,f2) @ wf + constc; log_softmax
__global__ __launch_bounds__(256) void k_final(
    const float* __restrict__ f0, const float* __restrict__ f1,
    const float* __restrict__ f2, const float* __restrict__ wf,
    const float* __restrict__ constc, float* __restrict__ out) {
  __shared__ __align__(16) float swf[NCLS * 388];  // [c][k], padded 384->388
  int tid = threadIdx.x;
  for (int i = tid; i < 384 * NCLS; i += 256) {
    int k = i >> 4, c = i & 15;
    swf[c * 388 + k] = wf[i];
  }
  __syncthreads();
  int r = blockIdx.x * 16 + (tid >> 4);
  int c = tid & 15;
  if (r >= N_NODES) return;
  float l = constc[c];
  const float4* q0 = (const float4*)(f0 + (size_t)r * HW_);
  const float4* q1 = (const float4*)(f1 + (size_t)r * HW_);
  const float4* q2 = (const float4*)(f2 + (size_t)r * HW_);
  const float4* wrow = (const float4*)(swf + c * 388);
  for (int kk = 0; kk < 32; kk++) {
    float4 a = q0[kk]; float4 w = wrow[kk];
    l += a.x * w.x + a.y * w.y + a.z * w.z + a.w * w.w;
  }
  for (int kk = 0; kk < 32; kk++) {
    float4 a = q1[kk]; float4 w = wrow[32 + kk];
    l += a.x * w.x + a.y * w.y + a.z * w.z + a.w * w.w;
  }
  for (int kk = 0; kk < 32; kk++) {
    float4 a = q2[kk]; float4 w = wrow[64 + kk];
    l += a.x * w.x + a.y * w.y + a.z * w.z + a.w * w.w;
  }
  float m = l;
  for (int o = 8; o >= 1; o >>= 1) m = fmaxf(m, __shfl_xor(m, o, 16));
  float s = expf(l - m);
  for (int o = 8; o >= 1; o >>= 1) s += __shfl_xor(s, o, 16);
  out[(size_t)r * NCLS + c] = (l - m) - logf(s);
}

// ---------------- launch ----------------
extern "C" void kernel_launch(void* const* d_in, const int* in_sizes, int n_in,
                              void* d_out, int out_size, void* d_ws, size_t ws_size,
                              hipStream_t stream) {
  const float* x   = (const float*)d_in[0];
  const int*   adj = (const int*)d_in[1];
  const float* av  = (const float*)d_in[2];
  const float* w1  = (const float*)d_in[3];
  const float* b1  = (const float*)d_in[4];
  const float* w2  = (const float*)d_in[5];
  const float* b2  = (const float*)d_in[6];
  const float* wf  = (const float*)d_in[7];
  const float* bf  = (const float*)d_in[8];
  float* out = (float*)d_out;

  char* ws = (char*)d_ws;
  size_t off = 0;
  auto alloc = [&](size_t bytes) -> void* {
    off = (off + 255) & ~(size_t)255;
    void* p = ws + off;
    off += bytes;
    return p;
  };

  // xb (bf16 x) is dead after GEMM1; F0/F1 are written by GEMM2 afterwards ->
  // alias them over xb's 51.2 MB region.
  __bf16* xb  = (__bf16*)alloc((size_t)N_NODES * FIN * 2);  // 51.2 MB
  float* F0   = (float*)xb;
  float* F1   = (float*)((char*)xb + (size_t)N_NODES * HW_ * 4);
  __bf16* a1b = (__bf16*)alloc((size_t)N_NODES * 384 * 2);
  __bf16* Ab  = (__bf16*)alloc((size_t)N_NODES * HW_ * 2);
  __bf16* Bb  = (__bf16*)alloc((size_t)N_NODES * HW_ * 2);
  __bf16* Cb  = (__bf16*)alloc((size_t)N_NODES * HW_ * 2);
  float* F2   = (float*)alloc((size_t)N_NODES * HW_ * 4);
  __bf16* w1t = (__bf16*)alloc((size_t)3 * 128 * FIN * 2);
  __bf16* w2t = (__bf16*)alloc((size_t)3 * 128 * 384 * 2);
  int* rowptr = (int*)alloc((size_t)(N_NODES + 1) * 4);
  int* wcur   = (int*)alloc((size_t)N_NODES * 4);
  int* cnt    = (int*)alloc((size_t)N_NODES * 4);
  int* bsum   = (int*)alloc((size_t)SCAN_NB * 4);
  int* bsumex = (int*)alloc((size_t)SCAN_NB * 4);
  int2* epack = (int2*)alloc((size_t)N_EDGES * 8);
  float* cc   = (float*)alloc(64);

  // CSR build (parallel scan)
  hipMemsetAsync(cnt, 0, (size_t)N_NODES * 4, stream);
  k_hist<<<(N_EDGES + 255) / 256, 256, 0, stream>>>(adj, cnt);
  k_scan_block<<<SCAN_NB, 256, 0, stream>>>(cnt, bsum);
  k_scan_top<<<1, 256, 0, stream>>>(bsum, bsumex);
  k_scan_fill<<<SCAN_NB, 256, 0, stream>>>(cnt, bsumex, rowptr, wcur);
  k_scatter<<<(N_EDGES + 255) / 256, 256, 0, stream>>>(adj, av, wcur, epack);
  k_const<<<1, 64, 0, stream>>>(b2, wf, bf, cc);

  // input/weight conversion
  k_xcast<<<(N_NODES * FIN / 8 + 255) / 256, 256, 0, stream>>>(x, xb, N_NODES * FIN / 8);
  k_wt<<<(3 * FIN * 128 + 255) / 256, 256, 0, stream>>>(w1, w1t, FIN);
  k_wt<<<(3 * 384 * 128 + 255) / 256, 256, 0, stream>>>(w2, w2t, 384);

  dim3 g1((N_NODES + 127) / 128, 3);
  int spmm_grid = (N_NODES + 3) / 4;

  // GEMM1: relu(x@w1+b1): blk0 -> a1b cols 0-127 (bf16); blk1 -> Ab; blk2 -> Bb
  gemm_mfma<true, false><<<g1, 256, 0, stream>>>(
      xb, N_NODES, FIN, w1t, b1, (void*)a1b, 384, Ab, HW_, Bb, HW_);
  // upper hops (xb dead from here)
  spmm_csr<false><<<spmm_grid, 256, 0, stream>>>(rowptr, epack, Ab, (void*)(a1b + 128), 384);
  spmm_csr<false><<<spmm_grid, 256, 0, stream>>>(rowptr, epack, Bb, (void*)Ab, HW_);
  spmm_csr<false><<<spmm_grid, 256, 0, stream>>>(rowptr, epack, Ab, (void*)(a1b + 256), 384);

  // GEMM2: a1b@w2 (bias folded into constc): blk0 -> F0 (fp32); blk1 -> Bb; blk2 -> Cb
  gemm_mfma<false, true><<<g1, 256, 0, stream>>>(
      a1b, N_NODES, 384, w2t, nullptr, (void*)F0, HW_, Bb, HW_, Cb, HW_);
  // bottom hops
  spmm_csr<true><<<spmm_grid, 256, 0, stream>>>(rowptr, epack, Bb, (void*)F1, HW_);
  spmm_csr<false><<<spmm_grid, 256, 0, stream>>>(rowptr, epack, Cb, (void*)Bb, HW_);
  spmm_csr<true><<<spmm_grid, 256, 0, stream>>>(rowptr, epack, Bb, (void*)F2, HW_);

  // final fused GEMM + log_softmax
  k_final<<<(N_NODES + 15) / 16, 256, 0, stream>>>(F0, F1, F2, wf, cc, out);
}

// Round 5
// 554.544 us; speedup vs baseline: 1.0659x; 1.0659x over previous
//
#include <hip/hip_runtime.h>
#include <hip/hip_bf16.h>
#include <cstdint>
#include <cstddef>

#define N_NODES 50000
#define N_EDGES 800000
#define FIN 512
#define HW_ 128
#define NCLS 16
#define SCAN_NB 196  // ceil(50000/256)

typedef __attribute__((ext_vector_type(4))) float floatx4;
typedef __attribute__((ext_vector_type(4))) int int4v;
typedef __bf16 bf16x8 __attribute__((ext_vector_type(8)));

__device__ __forceinline__ void glds16(const __bf16* g, __bf16* l) {
  __builtin_amdgcn_global_load_lds(
      (const __attribute__((address_space(1))) void*)g,
      (__attribute__((address_space(3))) void*)l, 16, 0, 0);
}

// ---------------- CSR build: histogram ----------------
__global__ void k_hist(const int* __restrict__ idx, int* __restrict__ cnt) {
  int e = blockIdx.x * blockDim.x + threadIdx.x;
  if (e < N_EDGES) atomicAdd(&cnt[idx[e]], 1);
}

// ---------------- parallel scan: per-block sums ----------------
__global__ __launch_bounds__(256) void k_scan_block(const int* __restrict__ cnt,
                                                    int* __restrict__ bsum) {
  int t = blockIdx.x * 256 + threadIdx.x;
  int v = (t < N_NODES) ? cnt[t] : 0;
#pragma unroll
  for (int o = 32; o >= 1; o >>= 1) v += __shfl_down(v, o);
  __shared__ int ws[4];
  if ((threadIdx.x & 63) == 0) ws[threadIdx.x >> 6] = v;
  __syncthreads();
  if (threadIdx.x == 0) bsum[blockIdx.x] = ws[0] + ws[1] + ws[2] + ws[3];
}

// ---------------- parallel scan: top-level exclusive scan ----------------
__global__ __launch_bounds__(256) void k_scan_top(const int* __restrict__ bsum,
                                                  int* __restrict__ bsumex) {
  int t = threadIdx.x;
  int lane = t & 63;
  int orig = (t < SCAN_NB) ? bsum[t] : 0;
  int v = orig;
#pragma unroll
  for (int o = 1; o < 64; o <<= 1) {
    int n = __shfl_up(v, o);
    if (lane >= o) v += n;
  }
  __shared__ int wt[4];
  if (lane == 63) wt[t >> 6] = v;
  __syncthreads();
  int add = 0;
  for (int w = 0; w < (t >> 6); w++) add += wt[w];
  if (t < SCAN_NB) bsumex[t] = v + add - orig;
}

// ---------------- parallel scan: fill rowptr + wcur ----------------
__global__ __launch_bounds__(256) void k_scan_fill(const int* __restrict__ cnt,
                                                   const int* __restrict__ bsumex,
                                                   int* __restrict__ rowptr,
                                                   int* __restrict__ wcur) {
  int t = blockIdx.x * 256 + threadIdx.x;
  int lane = threadIdx.x & 63;
  int c = (t < N_NODES) ? cnt[t] : 0;
  int v = c;
#pragma unroll
  for (int o = 1; o < 64; o <<= 1) {
    int n = __shfl_up(v, o);
    if (lane >= o) v += n;
  }
  __shared__ int wt[4];
  if (lane == 63) wt[threadIdx.x >> 6] = v;
  __syncthreads();
  int add = bsumex[blockIdx.x];
  for (int w = 0; w < (threadIdx.x >> 6); w++) add += wt[w];
  int ex = v - c + add;
  if (t < N_NODES) { rowptr[t] = ex; wcur[t] = ex; }
  if (t == 0) rowptr[N_NODES] = N_EDGES;
}

// ---------------- scatter edges (packed col+val) ----------------
__global__ void k_scatter(const int* __restrict__ idx, const float* __restrict__ vals,
                          int* __restrict__ wcur, int2* __restrict__ epack) {
  int e = blockIdx.x * blockDim.x + threadIdx.x;
  if (e < N_EDGES) {
    int r = idx[e];
    int c = idx[N_EDGES + e];
    int p = atomicAdd(&wcur[r], 1);
    epack[p] = make_int2(c, __float_as_int(vals[e]));
  }
}

// ---------------- fused prep: xcast | wt(w1) | wt(w2) | constc ----------------
#define PREP_NX 12500   // 50000*512/8 / 256
#define PREP_NW1 768    // 3*512*128 / 256
#define PREP_NW2 576    // 3*384*128 / 256
__global__ __launch_bounds__(256) void k_prep(
    const float* __restrict__ x, __bf16* __restrict__ xb,
    const float* __restrict__ w1, __bf16* __restrict__ w1t,
    const float* __restrict__ w2, __bf16* __restrict__ w2t,
    const float* __restrict__ b2, const float* __restrict__ wf,
    const float* __restrict__ bfv, float* __restrict__ cc) {
  int b = blockIdx.x;
  int tid = threadIdx.x;
  if (b < PREP_NX) {
    int t = b * 256 + tid;
    floatx4 a = *(const floatx4*)(x + (size_t)t * 8);
    floatx4 bb = *(const floatx4*)(x + (size_t)t * 8 + 4);
    union { bf16x8 v; int4v i; } u;
#pragma unroll
    for (int q = 0; q < 4; q++) { u.v[q] = (__bf16)a[q]; u.v[q + 4] = (__bf16)bb[q]; }
    *(int4v*)(xb + (size_t)t * 8) = u.i;
  } else if (b < PREP_NX + PREP_NW1) {
    int t = (b - PREP_NX) * 256 + tid;
    const int K = FIN;
    int i = t / (K * 128);
    int r = t - i * K * 128;
    int k = r >> 7, nn = r & 127;
    w1t[(size_t)i * 128 * K + (size_t)nn * K + k] = (__bf16)w1[t];
  } else if (b < PREP_NX + PREP_NW1 + PREP_NW2) {
    int t = (b - PREP_NX - PREP_NW1) * 256 + tid;
    const int K = 384;
    int i = t / (K * 128);
    int r = t - i * K * 128;
    int k = r >> 7, nn = r & 127;
    w2t[(size_t)i * 128 * K + (size_t)nn * K + k] = (__bf16)w2[t];
  } else {
    int c = tid;
    if (c < NCLS) {
      float s = bfv[c];
      for (int k = 0; k < 384; k++) s += b2[k] * wf[k * NCLS + c];
      cc[c] = s;
    }
  }
}

// ---------------- SpMM 256-wide: both hop-1 chains in one pass ---------------
// in: [N][256] bf16. cols 0-127 -> out_lo (stride slo), 128-255 -> out_hi.
__global__ __launch_bounds__(256) void spmm256(
    const int* __restrict__ rowptr, const int2* __restrict__ epack,
    const __bf16* __restrict__ in,
    __bf16* __restrict__ out_lo, int slo,
    __bf16* __restrict__ out_hi, int shi) {
  int row = (int)((blockIdx.x * (size_t)blockDim.x + threadIdx.x) >> 6);
  if (row >= N_NODES) return;
  int lane = threadIdx.x & 63;
  int g = lane >> 5, l = lane & 31;
  int s = rowptr[row], e = rowptr[row + 1];
  float a[8] = {0.f, 0.f, 0.f, 0.f, 0.f, 0.f, 0.f, 0.f};
  int i = s + g;
  for (; i + 2 < e; i += 4) {
    int2 e0 = epack[i];
    int2 e1 = epack[i + 2];
    bf16x8 p0 = *(const bf16x8*)(in + ((size_t)e0.x << 8) + 8 * l);
    bf16x8 p1 = *(const bf16x8*)(in + ((size_t)e1.x << 8) + 8 * l);
    float v0 = __int_as_float(e0.y), v1 = __int_as_float(e1.y);
#pragma unroll
    for (int u = 0; u < 8; u++) a[u] += v0 * (float)p0[u] + v1 * (float)p1[u];
  }
  for (; i < e; i += 2) {
    int2 e0 = epack[i];
    bf16x8 p0 = *(const bf16x8*)(in + ((size_t)e0.x << 8) + 8 * l);
    float v0 = __int_as_float(e0.y);
#pragma unroll
    for (int u = 0; u < 8; u++) a[u] += v0 * (float)p0[u];
  }
#pragma unroll
  for (int u = 0; u < 8; u++) a[u] += __shfl_xor(a[u], 32);
  if (g == 0) {
    union { bf16x8 v; int4v i; } u8;
#pragma unroll
    for (int q = 0; q < 8; q++) u8.v[q] = (__bf16)a[q];
    if (l < 16) *(int4v*)(out_lo + (size_t)row * slo + 8 * l) = u8.i;
    else        *(int4v*)(out_hi + (size_t)row * shi + 8 * (l - 16)) = u8.i;
  }
}

// ---------------- SpMM 128-wide (second hop) ----------------
__global__ __launch_bounds__(256) void spmm128(
    const int* __restrict__ rowptr, const int2* __restrict__ epack,
    const __bf16* __restrict__ in,
    __bf16* __restrict__ outp, int ostride) {
  int row = (int)((blockIdx.x * (size_t)blockDim.x + threadIdx.x) >> 6);
  if (row >= N_NODES) return;
  int lane = threadIdx.x & 63;
  int g = lane >> 4, l = lane & 15;
  int s = rowptr[row], e = rowptr[row + 1];
  float a[8] = {0.f, 0.f, 0.f, 0.f, 0.f, 0.f, 0.f, 0.f};
  int i = s + g;
  for (; i + 4 < e; i += 8) {
    int2 e0 = epack[i];
    int2 e1 = epack[i + 4];
    bf16x8 p0 = *(const bf16x8*)(in + ((size_t)e0.x << 7) + 8 * l);
    bf16x8 p1 = *(const bf16x8*)(in + ((size_t)e1.x << 7) + 8 * l);
    float v0 = __int_as_float(e0.y), v1 = __int_as_float(e1.y);
#pragma unroll
    for (int u = 0; u < 8; u++) a[u] += v0 * (float)p0[u] + v1 * (float)p1[u];
  }
  for (; i < e; i += 4) {
    int2 e0 = epack[i];
    bf16x8 p0 = *(const bf16x8*)(in + ((size_t)e0.x << 7) + 8 * l);
    float v0 = __int_as_float(e0.y);
#pragma unroll
    for (int u = 0; u < 8; u++) a[u] += v0 * (float)p0[u];
  }
#pragma unroll
  for (int u = 0; u < 8; u++) {
    a[u] += __shfl_xor(a[u], 16);
    a[u] += __shfl_xor(a[u], 32);
  }
  if (g == 0) {
    union { bf16x8 v; int4v i; } u8;
#pragma unroll
    for (int q = 0; q < 8; q++) u8.v[q] = (__bf16)a[q];
    *(int4v*)(outp + (size_t)row * ostride + 8 * l) = u8.i;
  }
}

// ---------------- MFMA bf16 GEMM, 128x128 tile, glds staging, 2-way LDS ------
// C[M,384] = act(A[M,K] @ W + bias). A bf16 [M][K]; W transposed Bt[3][128][K].
// All outputs bf16. blk0 -> out0/s0; blk1 -> out1/s1; blk2 -> out2/s2.
template <bool HASB>
__global__ __launch_bounds__(256) void gemm_mfma(
    const __bf16* __restrict__ Ab, int M, int K,
    const __bf16* __restrict__ Bt,
    const float* __restrict__ bias,
    __bf16* __restrict__ out0, int s0,
    __bf16* __restrict__ out1, int s1,
    __bf16* __restrict__ out2, int s2) {
  __shared__ __align__(16) __bf16 sA[128 * 32];
  __shared__ __align__(16) __bf16 sB[128 * 32];
  int tid = threadIdx.x;
  int m0 = blockIdx.x * 128;
  int blk = blockIdx.y;
  const __bf16* Bblk = Bt + (size_t)blk * 128 * K;
  int wave = tid >> 6, lane = tid & 63;
  int wm = (wave & 1) * 64, wn = (wave >> 1) * 64;
  floatx4 acc[4][4] = {};

  // staging: row rA = lane>>2, LDS slot lane&3; global chunk XOR-swizzled so
  // fragment reads are uniform 2-way (free): gch = (lane&3) ^ ((rA>>1)&3).
  int rA = lane >> 2;
  int gch = (lane & 3) ^ ((lane >> 3) & 3);
  int r0 = wave * 32 + rA;
  int r1 = r0 + 16;
  int gm0 = m0 + r0; gm0 = (gm0 < M) ? gm0 : (M - 1);
  int gm1 = m0 + r1; gm1 = (gm1 < M) ? gm1 : (M - 1);
  const __bf16* pa0 = Ab + (size_t)gm0 * K + gch * 8;
  const __bf16* pa1 = Ab + (size_t)gm1 * K + gch * 8;
  const __bf16* pb0 = Bblk + (size_t)r0 * K + gch * 8;
  const __bf16* pb1 = Bblk + (size_t)r1 * K + gch * 8;
  __bf16* lA0 = sA + wave * 1024;
  __bf16* lA1 = sA + wave * 1024 + 512;
  __bf16* lB0 = sB + wave * 1024;
  __bf16* lB1 = sB + wave * 1024 + 512;

  // fragment addressing: chunk fg of row R lives at slot fg ^ ((R>>1)&3)
  int fm = lane & 15, fg = lane >> 4;
  int sloto = (fg ^ ((fm >> 1) & 3)) * 8;

  for (int k0 = 0; k0 < K; k0 += 32) {
    __syncthreads();   // prior iter's ds_reads done before overwrite
    glds16(pa0 + k0, lA0);
    glds16(pa1 + k0, lA1);
    glds16(pb0 + k0, lB0);
    glds16(pb1 + k0, lB1);
    __syncthreads();   // drains vmcnt (global_load_lds) for all waves

    bf16x8 af[4], bfr[4];
#pragma unroll
    for (int mt = 0; mt < 4; mt++)
      af[mt] = *(const bf16x8*)(sA + (wm + mt * 16 + fm) * 32 + sloto);
#pragma unroll
    for (int nt = 0; nt < 4; nt++)
      bfr[nt] = *(const bf16x8*)(sB + (wn + nt * 16 + fm) * 32 + sloto);
#pragma unroll
    for (int mt = 0; mt < 4; mt++)
#pragma unroll
      for (int nt = 0; nt < 4; nt++)
        acc[mt][nt] = __builtin_amdgcn_mfma_f32_16x16x32_bf16(af[mt], bfr[nt], acc[mt][nt], 0, 0, 0);
  }

  // epilogue: C/D layout col=lane&15, row=quad*4+reg (m89-verified)
  int colb = lane & 15, rbase = (lane >> 4) << 2;
  const float* bp = HASB ? (bias + blk * 128) : nullptr;
  __bf16* o = (blk == 0) ? out0 : ((blk == 1) ? out1 : out2);
  int os = (blk == 0) ? s0 : ((blk == 1) ? s1 : s2);
#pragma unroll
  for (int mt = 0; mt < 4; mt++)
#pragma unroll
    for (int r = 0; r < 4; r++) {
      int gm = m0 + wm + mt * 16 + rbase + r;
      if (gm >= M) continue;
#pragma unroll
      for (int nt = 0; nt < 4; nt++) {
        int gc = wn + nt * 16 + colb;
        float vv = acc[mt][nt][r];
        if (HASB) { vv += bp[gc]; vv = fmaxf(vv, 0.f); }
        o[(size_t)gm * os + gc] = (__bf16)vv;
      }
    }
}

// ---------------- final: logits = concat(f0,f1,f2) @ wf + constc; log_softmax
__global__ __launch_bounds__(256) void k_final(
    const __bf16* __restrict__ f0, const __bf16* __restrict__ f1,
    const __bf16* __restrict__ f2, const float* __restrict__ wf,
    const float* __restrict__ constc, float* __restrict__ out) {
  __shared__ __align__(16) float swf[NCLS * 388];  // [c][k], padded 384->388
  int tid = threadIdx.x;
  for (int i = tid; i < 384 * NCLS; i += 256) {
    int k = i >> 4, c = i & 15;
    swf[c * 388 + k] = wf[i];
  }
  __syncthreads();
  int r = blockIdx.x * 16 + (tid >> 4);
  int c = tid & 15;
  if (r >= N_NODES) return;
  float l = constc[c];
  const bf16x8* q0 = (const bf16x8*)(f0 + (size_t)r * HW_);
  const bf16x8* q1 = (const bf16x8*)(f1 + (size_t)r * HW_);
  const bf16x8* q2 = (const bf16x8*)(f2 + (size_t)r * HW_);
  const float* wrow = swf + c * 388;
#pragma unroll 4
  for (int kk = 0; kk < 16; kk++) {
    bf16x8 a = q0[kk];
#pragma unroll
    for (int u = 0; u < 8; u++) l += (float)a[u] * wrow[kk * 8 + u];
  }
#pragma unroll 4
  for (int kk = 0; kk < 16; kk++) {
    bf16x8 a = q1[kk];
#pragma unroll
    for (int u = 0; u < 8; u++) l += (float)a[u] * wrow[128 + kk * 8 + u];
  }
#pragma unroll 4
  for (int kk = 0; kk < 16; kk++) {
    bf16x8 a = q2[kk];
#pragma unroll
    for (int u = 0; u < 8; u++) l += (float)a[u] * wrow[256 + kk * 8 + u];
  }
  float m = l;
  for (int o = 8; o >= 1; o >>= 1) m = fmaxf(m, __shfl_xor(m, o, 16));
  float s = expf(l - m);
  for (int o = 8; o >= 1; o >>= 1) s += __shfl_xor(s, o, 16);
  out[(size_t)r * NCLS + c] = (l - m) - logf(s);
}

// ---------------- launch ----------------
extern "C" void kernel_launch(void* const* d_in, const int* in_sizes, int n_in,
                              void* d_out, int out_size, void* d_ws, size_t ws_size,
                              hipStream_t stream) {
  const float* x   = (const float*)d_in[0];
  const int*   adj = (const int*)d_in[1];
  const float* av  = (const float*)d_in[2];
  const float* w1  = (const float*)d_in[3];
  const float* b1  = (const float*)d_in[4];
  const float* w2  = (const float*)d_in[5];
  const float* b2  = (const float*)d_in[6];
  const float* wf  = (const float*)d_in[7];
  const float* bf  = (const float*)d_in[8];
  float* out = (float*)d_out;

  char* ws = (char*)d_ws;
  size_t off = 0;
  auto alloc = [&](size_t bytes) -> void* {
    off = (off + 255) & ~(size_t)255;
    void* p = ws + off;
    off += bytes;
    return p;
  };

  // xb (51.2 MB) dead after GEMM1 -> alias F0/F1/F2 (bf16, 12.8 MB each) on it.
  __bf16* xb  = (__bf16*)alloc((size_t)N_NODES * FIN * 2);
  __bf16* F0  = xb;
  __bf16* F1  = xb + (size_t)N_NODES * HW_;
  __bf16* F2  = xb + (size_t)2 * N_NODES * HW_;
  __bf16* a1b = (__bf16*)alloc((size_t)N_NODES * 384 * 2);
  __bf16* ABb = (__bf16*)alloc((size_t)N_NODES * 256 * 2);  // GEMM blk1|blk2; reused by both chains
  __bf16* Tb  = (__bf16*)alloc((size_t)N_NODES * HW_ * 2);  // 2-hop intermediate
  __bf16* w1t = (__bf16*)alloc((size_t)3 * 128 * FIN * 2);
  __bf16* w2t = (__bf16*)alloc((size_t)3 * 128 * 384 * 2);
  int* rowptr = (int*)alloc((size_t)(N_NODES + 1) * 4);
  int* wcur   = (int*)alloc((size_t)N_NODES * 4);
  int* cnt    = (int*)alloc((size_t)N_NODES * 4);
  int* bsum   = (int*)alloc((size_t)SCAN_NB * 4);
  int* bsumex = (int*)alloc((size_t)SCAN_NB * 4);
  int2* epack = (int2*)alloc((size_t)N_EDGES * 8);
  float* cc   = (float*)alloc(64);

  // CSR build (parallel scan)
  hipMemsetAsync(cnt, 0, (size_t)N_NODES * 4, stream);
  k_hist<<<(N_EDGES + 255) / 256, 256, 0, stream>>>(adj, cnt);
  k_scan_block<<<SCAN_NB, 256, 0, stream>>>(cnt, bsum);
  k_scan_top<<<1, 256, 0, stream>>>(bsum, bsumex);
  k_scan_fill<<<SCAN_NB, 256, 0, stream>>>(cnt, bsumex, rowptr, wcur);
  k_scatter<<<(N_EDGES + 255) / 256, 256, 0, stream>>>(adj, av, wcur, epack);

  // fused prep: xcast + both weight transposes + constc
  k_prep<<<PREP_NX + PREP_NW1 + PREP_NW2 + 1, 256, 0, stream>>>(
      x, xb, w1, w1t, w2, w2t, b2, wf, bf, cc);

  dim3 g1((N_NODES + 127) / 128, 3);
  int spmm_grid = (N_NODES + 3) / 4;

  // GEMM1: relu(x@w1+b1): blk0 -> a1 cols 0-127; blk1 -> ABb lo; blk2 -> ABb hi
  gemm_mfma<true><<<g1, 256, 0, stream>>>(
      xb, N_NODES, FIN, w1t, b1, a1b, 384, ABb, 256, ABb + 128, 256);
  // upper hops: pass1 (256-wide) -> a1 cols 128-255 + Tb; pass2 -> a1 cols 256-383
  spmm256<<<spmm_grid, 256, 0, stream>>>(rowptr, epack, ABb, a1b + 128, 384, Tb, HW_);
  spmm128<<<spmm_grid, 256, 0, stream>>>(rowptr, epack, Tb, a1b + 256, 384);

  // GEMM2: a1@w2 (bias folded into constc): blk0 -> F0; blk1|blk2 -> ABb
  gemm_mfma<false><<<g1, 256, 0, stream>>>(
      a1b, N_NODES, 384, w2t, nullptr, F0, HW_, ABb, 256, ABb + 128, 256);
  // bottom hops: pass1 -> F1 + Tb; pass2 -> F2
  spmm256<<<spmm_grid, 256, 0, stream>>>(rowptr, epack, ABb, F1, HW_, Tb, HW_);
  spmm128<<<spmm_grid, 256, 0, stream>>>(rowptr, epack, Tb, F2, HW_);

  // final fused GEMM + log_softmax
  k_final<<<(N_NODES + 15) / 16, 256, 0, stream>>>(F0, F1, F2, wf, cc, out);
}

// Round 6
// 548.200 us; speedup vs baseline: 1.0782x; 1.0116x over previous
//
#include <hip/hip_runtime.h>
#include <hip/hip_bf16.h>
#include <cstdint>
#include <cstddef>

#define N_NODES 50000
#define N_EDGES 800000
#define FIN 512
#define HW_ 128
#define NCLS 16
#define SCAN_NB 196  // ceil(50000/256)

typedef __attribute__((ext_vector_type(4))) float floatx4;
typedef __attribute__((ext_vector_type(4))) int int4v;
typedef __bf16 bf16x8 __attribute__((ext_vector_type(8)));

__device__ __forceinline__ void glds16(const __bf16* g, __bf16* l) {
  __builtin_amdgcn_global_load_lds(
      (const __attribute__((address_space(1))) void*)g,
      (__attribute__((address_space(3))) void*)l, 16, 0, 0);
}

// ---------------- fused: histogram + xcast + wt(w1) + wt(w2) + constc --------
#define HIST_NB 3125    // 800000 / 256
#define PREP_NX 12500   // 50000*512/8 / 256
#define PREP_NW1 768    // 3*512*128 / 256
#define PREP_NW2 576    // 3*384*128 / 256
__global__ __launch_bounds__(256) void k_histprep(
    const int* __restrict__ idx, int* __restrict__ cnt,
    const float* __restrict__ x, __bf16* __restrict__ xb,
    const float* __restrict__ w1, __bf16* __restrict__ w1t,
    const float* __restrict__ w2, __bf16* __restrict__ w2t,
    const float* __restrict__ b2, const float* __restrict__ wf,
    const float* __restrict__ bfv, float* __restrict__ cc) {
  int b = blockIdx.x;
  int tid = threadIdx.x;
  if (b < HIST_NB) {
    int e = b * 256 + tid;
    if (e < N_EDGES) atomicAdd(&cnt[idx[e]], 1);
  } else if (b < HIST_NB + PREP_NX) {
    int t = (b - HIST_NB) * 256 + tid;
    floatx4 a = *(const floatx4*)(x + (size_t)t * 8);
    floatx4 bb = *(const floatx4*)(x + (size_t)t * 8 + 4);
    union { bf16x8 v; int4v i; } u;
#pragma unroll
    for (int q = 0; q < 4; q++) { u.v[q] = (__bf16)a[q]; u.v[q + 4] = (__bf16)bb[q]; }
    *(int4v*)(xb + (size_t)t * 8) = u.i;
  } else if (b < HIST_NB + PREP_NX + PREP_NW1) {
    int t = (b - HIST_NB - PREP_NX) * 256 + tid;
    const int K = FIN;
    int i = t / (K * 128);
    int r = t - i * K * 128;
    int k = r >> 7, nn = r & 127;
    w1t[(size_t)i * 128 * K + (size_t)nn * K + k] = (__bf16)w1[t];
  } else if (b < HIST_NB + PREP_NX + PREP_NW1 + PREP_NW2) {
    int t = (b - HIST_NB - PREP_NX - PREP_NW1) * 256 + tid;
    const int K = 384;
    int i = t / (K * 128);
    int r = t - i * K * 128;
    int k = r >> 7, nn = r & 127;
    w2t[(size_t)i * 128 * K + (size_t)nn * K + k] = (__bf16)w2[t];
  } else {
    int c = tid;
    if (c < NCLS) {
      float s = bfv[c];
      for (int k = 0; k < 384; k++) s += b2[k] * wf[k * NCLS + c];
      cc[c] = s;
    }
  }
}

// ---------------- parallel scan: per-block sums ----------------
__global__ __launch_bounds__(256) void k_scan_block(const int* __restrict__ cnt,
                                                    int* __restrict__ bsum) {
  int t = blockIdx.x * 256 + threadIdx.x;
  int v = (t < N_NODES) ? cnt[t] : 0;
#pragma unroll
  for (int o = 32; o >= 1; o >>= 1) v += __shfl_down(v, o);
  __shared__ int ws[4];
  if ((threadIdx.x & 63) == 0) ws[threadIdx.x >> 6] = v;
  __syncthreads();
  if (threadIdx.x == 0) bsum[blockIdx.x] = ws[0] + ws[1] + ws[2] + ws[3];
}

// ---------------- scan fill (inlines top-level scan of bsum) ----------------
__global__ __launch_bounds__(256) void k_scan_fill(const int* __restrict__ cnt,
                                                   const int* __restrict__ bsum,
                                                   int* __restrict__ rowptr,
                                                   int* __restrict__ wcur) {
  int tid = threadIdx.x;
  int lane = tid & 63;
  // cross-block offset: sum of bsum[0..blockIdx.x)
  int pv = (tid < blockIdx.x && tid < SCAN_NB) ? bsum[tid] : 0;
#pragma unroll
  for (int o = 32; o >= 1; o >>= 1) pv += __shfl_down(pv, o);
  __shared__ int ps[4];
  if (lane == 0) ps[tid >> 6] = pv;
  // intra-block scan of cnt
  int t = blockIdx.x * 256 + tid;
  int c = (t < N_NODES) ? cnt[t] : 0;
  int v = c;
#pragma unroll
  for (int o = 1; o < 64; o <<= 1) {
    int n = __shfl_up(v, o);
    if (lane >= o) v += n;
  }
  __shared__ int wt[4];
  if (lane == 63) wt[tid >> 6] = v;
  __syncthreads();
  int add = ps[0] + ps[1] + ps[2] + ps[3];
  for (int w = 0; w < (tid >> 6); w++) add += wt[w];
  int ex = v - c + add;
  if (t < N_NODES) { rowptr[t] = ex; wcur[t] = ex; }
  if (t == 0) rowptr[N_NODES] = N_EDGES;
}

// ---------------- scatter edges (packed col+val) ----------------
__global__ void k_scatter(const int* __restrict__ idx, const float* __restrict__ vals,
                          int* __restrict__ wcur, int2* __restrict__ epack) {
  int e = blockIdx.x * blockDim.x + threadIdx.x;
  if (e < N_EDGES) {
    int r = idx[e];
    int c = idx[N_EDGES + e];
    int p = atomicAdd(&wcur[r], 1);
    epack[p] = make_int2(c, __float_as_int(vals[e]));
  }
}

// ---------------- SpMM 256-wide: both hop-1 chains; 4 gathers in flight ------
__global__ __launch_bounds__(256) void spmm256(
    const int* __restrict__ rowptr, const int2* __restrict__ epack,
    const __bf16* __restrict__ in,
    __bf16* __restrict__ out_lo, int slo,
    __bf16* __restrict__ out_hi, int shi) {
  int row = (int)((blockIdx.x * (size_t)blockDim.x + threadIdx.x) >> 6);
  if (row >= N_NODES) return;
  int lane = threadIdx.x & 63;
  int g = lane >> 5, l = lane & 31;
  int s = rowptr[row], e = rowptr[row + 1];
  float a[8] = {0.f, 0.f, 0.f, 0.f, 0.f, 0.f, 0.f, 0.f};
  int i = s + g;
  for (; i + 6 < e; i += 8) {
    int2 e0 = epack[i], e1 = epack[i + 2], e2 = epack[i + 4], e3 = epack[i + 6];
    bf16x8 p0 = *(const bf16x8*)(in + ((size_t)e0.x << 8) + 8 * l);
    bf16x8 p1 = *(const bf16x8*)(in + ((size_t)e1.x << 8) + 8 * l);
    bf16x8 p2 = *(const bf16x8*)(in + ((size_t)e2.x << 8) + 8 * l);
    bf16x8 p3 = *(const bf16x8*)(in + ((size_t)e3.x << 8) + 8 * l);
    float v0 = __int_as_float(e0.y), v1 = __int_as_float(e1.y);
    float v2 = __int_as_float(e2.y), v3 = __int_as_float(e3.y);
#pragma unroll
    for (int u = 0; u < 8; u++)
      a[u] += v0 * (float)p0[u] + v1 * (float)p1[u] + v2 * (float)p2[u] + v3 * (float)p3[u];
  }
  for (; i < e; i += 2) {
    int2 e0 = epack[i];
    bf16x8 p0 = *(const bf16x8*)(in + ((size_t)e0.x << 8) + 8 * l);
    float v0 = __int_as_float(e0.y);
#pragma unroll
    for (int u = 0; u < 8; u++) a[u] += v0 * (float)p0[u];
  }
#pragma unroll
  for (int u = 0; u < 8; u++) a[u] += __shfl_xor(a[u], 32);
  if (g == 0) {
    union { bf16x8 v; int4v i; } u8;
#pragma unroll
    for (int q = 0; q < 8; q++) u8.v[q] = (__bf16)a[q];
    if (l < 16) *(int4v*)(out_lo + (size_t)row * slo + 8 * l) = u8.i;
    else        *(int4v*)(out_hi + (size_t)row * shi + 8 * (l - 16)) = u8.i;
  }
}

// ---------------- SpMM 128-wide; 4 gathers in flight per group ---------------
__global__ __launch_bounds__(256) void spmm128(
    const int* __restrict__ rowptr, const int2* __restrict__ epack,
    const __bf16* __restrict__ in,
    __bf16* __restrict__ outp, int ostride) {
  int row = (int)((blockIdx.x * (size_t)blockDim.x + threadIdx.x) >> 6);
  if (row >= N_NODES) return;
  int lane = threadIdx.x & 63;
  int g = lane >> 4, l = lane & 15;
  int s = rowptr[row], e = rowptr[row + 1];
  float a[8] = {0.f, 0.f, 0.f, 0.f, 0.f, 0.f, 0.f, 0.f};
  int i = s + g;
  for (; i + 12 < e; i += 16) {
    int2 e0 = epack[i], e1 = epack[i + 4], e2 = epack[i + 8], e3 = epack[i + 12];
    bf16x8 p0 = *(const bf16x8*)(in + ((size_t)e0.x << 7) + 8 * l);
    bf16x8 p1 = *(const bf16x8*)(in + ((size_t)e1.x << 7) + 8 * l);
    bf16x8 p2 = *(const bf16x8*)(in + ((size_t)e2.x << 7) + 8 * l);
    bf16x8 p3 = *(const bf16x8*)(in + ((size_t)e3.x << 7) + 8 * l);
    float v0 = __int_as_float(e0.y), v1 = __int_as_float(e1.y);
    float v2 = __int_as_float(e2.y), v3 = __int_as_float(e3.y);
#pragma unroll
    for (int u = 0; u < 8; u++)
      a[u] += v0 * (float)p0[u] + v1 * (float)p1[u] + v2 * (float)p2[u] + v3 * (float)p3[u];
  }
  for (; i < e; i += 4) {
    int2 e0 = epack[i];
    bf16x8 p0 = *(const bf16x8*)(in + ((size_t)e0.x << 7) + 8 * l);
    float v0 = __int_as_float(e0.y);
#pragma unroll
    for (int u = 0; u < 8; u++) a[u] += v0 * (float)p0[u];
  }
#pragma unroll
  for (int u = 0; u < 8; u++) {
    a[u] += __shfl_xor(a[u], 16);
    a[u] += __shfl_xor(a[u], 32);
  }
  if (g == 0) {
    union { bf16x8 v; int4v i; } u8;
#pragma unroll
    for (int q = 0; q < 8; q++) u8.v[q] = (__bf16)a[q];
    *(int4v*)(outp + (size_t)row * ostride + 8 * l) = u8.i;
  }
}

// ---------------- MFMA bf16 GEMM, 128x128 tile, glds staging, 2-way LDS ------
template <bool HASB>
__global__ __launch_bounds__(256) void gemm_mfma(
    const __bf16* __restrict__ Ab, int M, int K,
    const __bf16* __restrict__ Bt,
    const float* __restrict__ bias,
    __bf16* __restrict__ out0, int s0,
    __bf16* __restrict__ out1, int s1,
    __bf16* __restrict__ out2, int s2) {
  __shared__ __align__(16) __bf16 sA[128 * 32];
  __shared__ __align__(16) __bf16 sB[128 * 32];
  int tid = threadIdx.x;
  int m0 = blockIdx.x * 128;
  int blk = blockIdx.y;
  const __bf16* Bblk = Bt + (size_t)blk * 128 * K;
  int wave = tid >> 6, lane = tid & 63;
  int wm = (wave & 1) * 64, wn = (wave >> 1) * 64;
  floatx4 acc[4][4] = {};

  int rA = lane >> 2;
  int gch = (lane & 3) ^ ((lane >> 3) & 3);
  int r0 = wave * 32 + rA;
  int r1 = r0 + 16;
  int gm0 = m0 + r0; gm0 = (gm0 < M) ? gm0 : (M - 1);
  int gm1 = m0 + r1; gm1 = (gm1 < M) ? gm1 : (M - 1);
  const __bf16* pa0 = Ab + (size_t)gm0 * K + gch * 8;
  const __bf16* pa1 = Ab + (size_t)gm1 * K + gch * 8;
  const __bf16* pb0 = Bblk + (size_t)r0 * K + gch * 8;
  const __bf16* pb1 = Bblk + (size_t)r1 * K + gch * 8;
  __bf16* lA0 = sA + wave * 1024;
  __bf16* lA1 = sA + wave * 1024 + 512;
  __bf16* lB0 = sB + wave * 1024;
  __bf16* lB1 = sB + wave * 1024 + 512;

  int fm = lane & 15, fg = lane >> 4;
  int sloto = (fg ^ ((fm >> 1) & 3)) * 8;

  for (int k0 = 0; k0 < K; k0 += 32) {
    __syncthreads();
    glds16(pa0 + k0, lA0);
    glds16(pa1 + k0, lA1);
    glds16(pb0 + k0, lB0);
    glds16(pb1 + k0, lB1);
    __syncthreads();

    bf16x8 af[4], bfr[4];
#pragma unroll
    for (int mt = 0; mt < 4; mt++)
      af[mt] = *(const bf16x8*)(sA + (wm + mt * 16 + fm) * 32 + sloto);
#pragma unroll
    for (int nt = 0; nt < 4; nt++)
      bfr[nt] = *(const bf16x8*)(sB + (wn + nt * 16 + fm) * 32 + sloto);
#pragma unroll
    for (int mt = 0; mt < 4; mt++)
#pragma unroll
      for (int nt = 0; nt < 4; nt++)
        acc[mt][nt] = __builtin_amdgcn_mfma_f32_16x16x32_bf16(af[mt], bfr[nt], acc[mt][nt], 0, 0, 0);
  }

  int colb = lane & 15, rbase = (lane >> 4) << 2;
  const float* bp = HASB ? (bias + blk * 128) : nullptr;
  __bf16* o = (blk == 0) ? out0 : ((blk == 1) ? out1 : out2);
  int os = (blk == 0) ? s0 : ((blk == 1) ? s1 : s2);
#pragma unroll
  for (int mt = 0; mt < 4; mt++)
#pragma unroll
    for (int r = 0; r < 4; r++) {
      int gm = m0 + wm + mt * 16 + rbase + r;
      if (gm >= M) continue;
#pragma unroll
      for (int nt = 0; nt < 4; nt++) {
        int gc = wn + nt * 16 + colb;
        float vv = acc[mt][nt][r];
        if (HASB) { vv += bp[gc]; vv = fmaxf(vv, 0.f); }
        o[(size_t)gm * os + gc] = (__bf16)vv;
      }
    }
}

// ---------------- final: logits = concat(f0,f1,f2) @ wf + constc; log_softmax
__global__ __launch_bounds__(256) void k_final(
    const __bf16* __restrict__ f0, const __bf16* __restrict__ f1,
    const __bf16* __restrict__ f2, const float* __restrict__ wf,
    const float* __restrict__ constc, float* __restrict__ out) {
  __shared__ __align__(16) float swf[NCLS * 388];  // [c][k], padded
  int tid = threadIdx.x;
  for (int i = tid; i < 384 * NCLS; i += 256) {
    int k = i >> 4, c = i & 15;
    swf[c * 388 + k] = wf[i];
  }
  __syncthreads();
  int r = blockIdx.x * 16 + (tid >> 4);
  int c = tid & 15;
  if (r >= N_NODES) return;
  float l = constc[c];
  const bf16x8* q0 = (const bf16x8*)(f0 + (size_t)r * HW_);
  const bf16x8* q1 = (const bf16x8*)(f1 + (size_t)r * HW_);
  const bf16x8* q2 = (const bf16x8*)(f2 + (size_t)r * HW_);
  const float* wrow = swf + c * 388;
#pragma unroll 4
  for (int kk = 0; kk < 16; kk++) {
    bf16x8 a = q0[kk];
#pragma unroll
    for (int u = 0; u < 8; u++) l += (float)a[u] * wrow[kk * 8 + u];
  }
#pragma unroll 4
  for (int kk = 0; kk < 16; kk++) {
    bf16x8 a = q1[kk];
#pragma unroll
    for (int u = 0; u < 8; u++) l += (float)a[u] * wrow[128 + kk * 8 + u];
  }
#pragma unroll 4
  for (int kk = 0; kk < 16; kk++) {
    bf16x8 a = q2[kk];
#pragma unroll
    for (int u = 0; u < 8; u++) l += (float)a[u] * wrow[256 + kk * 8 + u];
  }
  float m = l;
  for (int o = 8; o >= 1; o >>= 1) m = fmaxf(m, __shfl_xor(m, o, 16));
  float s = expf(l - m);
  for (int o = 8; o >= 1; o >>= 1) s += __shfl_xor(s, o, 16);
  out[(size_t)r * NCLS + c] = (l - m) - logf(s);
}

// ---------------- launch ----------------
extern "C" void kernel_launch(void* const* d_in, const int* in_sizes, int n_in,
                              void* d_out, int out_size, void* d_ws, size_t ws_size,
                              hipStream_t stream) {
  const float* x   = (const float*)d_in[0];
  const int*   adj = (const int*)d_in[1];
  const float* av  = (const float*)d_in[2];
  const float* w1  = (const float*)d_in[3];
  const float* b1  = (const float*)d_in[4];
  const float* w2  = (const float*)d_in[5];
  const float* b2  = (const float*)d_in[6];
  const float* wf  = (const float*)d_in[7];
  const float* bf  = (const float*)d_in[8];
  float* out = (float*)d_out;

  char* ws = (char*)d_ws;
  size_t off = 0;
  auto alloc = [&](size_t bytes) -> void* {
    off = (off + 255) & ~(size_t)255;
    void* p = ws + off;
    off += bytes;
    return p;
  };

  // xb (51.2 MB) dead after GEMM1 -> alias F0/F1/F2 (bf16, 12.8 MB each) on it.
  __bf16* xb  = (__bf16*)alloc((size_t)N_NODES * FIN * 2);
  __bf16* F0  = xb;
  __bf16* F1  = xb + (size_t)N_NODES * HW_;
  __bf16* F2  = xb + (size_t)2 * N_NODES * HW_;
  __bf16* a1b = (__bf16*)alloc((size_t)N_NODES * 384 * 2);
  __bf16* ABb = (__bf16*)alloc((size_t)N_NODES * 256 * 2);
  __bf16* Tb  = (__bf16*)alloc((size_t)N_NODES * HW_ * 2);
  __bf16* w1t = (__bf16*)alloc((size_t)3 * 128 * FIN * 2);
  __bf16* w2t = (__bf16*)alloc((size_t)3 * 128 * 384 * 2);
  int* rowptr = (int*)alloc((size_t)(N_NODES + 1) * 4);
  int* wcur   = (int*)alloc((size_t)N_NODES * 4);
  int* cnt    = (int*)alloc((size_t)N_NODES * 4);
  int* bsum   = (int*)alloc((size_t)SCAN_NB * 4);
  int2* epack = (int2*)alloc((size_t)N_EDGES * 8);
  float* cc   = (float*)alloc(64);

  // CSR build + prep (fused): memset, hist|prep, scan_block, scan_fill, scatter
  hipMemsetAsync(cnt, 0, (size_t)N_NODES * 4, stream);
  k_histprep<<<HIST_NB + PREP_NX + PREP_NW1 + PREP_NW2 + 1, 256, 0, stream>>>(
      adj, cnt, x, xb, w1, w1t, w2, w2t, b2, wf, bf, cc);
  k_scan_block<<<SCAN_NB, 256, 0, stream>>>(cnt, bsum);
  k_scan_fill<<<SCAN_NB, 256, 0, stream>>>(cnt, bsum, rowptr, wcur);
  k_scatter<<<(N_EDGES + 255) / 256, 256, 0, stream>>>(adj, av, wcur, epack);

  dim3 g1((N_NODES + 127) / 128, 3);
  int spmm_grid = (N_NODES + 3) / 4;

  // GEMM1: relu(x@w1+b1): blk0 -> a1 cols 0-127; blk1 -> ABb lo; blk2 -> ABb hi
  gemm_mfma<true><<<g1, 256, 0, stream>>>(
      xb, N_NODES, FIN, w1t, b1, a1b, 384, ABb, 256, ABb + 128, 256);
  spmm256<<<spmm_grid, 256, 0, stream>>>(rowptr, epack, ABb, a1b + 128, 384, Tb, HW_);
  spmm128<<<spmm_grid, 256, 0, stream>>>(rowptr, epack, Tb, a1b + 256, 384);

  // GEMM2: a1@w2 (bias folded into constc): blk0 -> F0; blk1|blk2 -> ABb
  gemm_mfma<false><<<g1, 256, 0, stream>>>(
      a1b, N_NODES, 384, w2t, nullptr, F0, HW_, ABb, 256, ABb + 128, 256);
  spmm256<<<spmm_grid, 256, 0, stream>>>(rowptr, epack, ABb, F1, HW_, Tb, HW_);
  spmm128<<<spmm_grid, 256, 0, stream>>>(rowptr, epack, Tb, F2, HW_);

  // final fused GEMM + log_softmax
  k_final<<<(N_NODES + 15) / 16, 256, 0, stream>>>(F0, F1, F2, wf, cc, out);
}

// Round 7
// 527.509 us; speedup vs baseline: 1.1205x; 1.0392x over previous
//
#include <hip/hip_runtime.h>
#include <hip/hip_bf16.h>
#include <cstdint>
#include <cstddef>

#define N_NODES 50000
#define N_EDGES 800000
#define FIN 512
#define HW_ 128
#define NCLS 16
#define SCAN_NB 196  // ceil(50000/256)

typedef __attribute__((ext_vector_type(4))) float floatx4;
typedef __attribute__((ext_vector_type(4))) int int4v;
typedef __bf16 bf16x8 __attribute__((ext_vector_type(8)));

__device__ __forceinline__ void glds16(const __bf16* g, __bf16* l) {
  __builtin_amdgcn_global_load_lds(
      (const __attribute__((address_space(1))) void*)g,
      (__attribute__((address_space(3))) void*)l, 16, 0, 0);
}

// ---------------- rank: hist + per-edge rank (coalesced write) ----------------
__global__ __launch_bounds__(256) void k_rank(const int* __restrict__ idx,
                                              int* __restrict__ cnt,
                                              int* __restrict__ rank) {
  int e = blockIdx.x * 1024 + threadIdx.x;
#pragma unroll
  for (int u = 0; u < 4; u++) {
    int ee = e + u * 256;
    if (ee < N_EDGES) rank[ee] = atomicAdd(&cnt[idx[ee]], 1);
  }
}

// ---------------- prep: xcast | LDS-tiled w1/w2 transpose | constc ------------
#define PREP_NX 12500          // 50000*512/8 / 256
#define PREP_NT1 48            // 3 * (512/64) * (128/64)
#define PREP_NT2 36            // 3 * (384/64) * (128/64)
__global__ __launch_bounds__(256) void k_prep(
    const float* __restrict__ x, __bf16* __restrict__ xb,
    const float* __restrict__ w1, __bf16* __restrict__ w1t,
    const float* __restrict__ w2, __bf16* __restrict__ w2t,
    const float* __restrict__ b2, const float* __restrict__ wf,
    const float* __restrict__ bfv, float* __restrict__ cc) {
  int b = blockIdx.x;
  int tid = threadIdx.x;
  if (b < PREP_NX) {
    int t = b * 256 + tid;
    floatx4 a = *(const floatx4*)(x + (size_t)t * 8);
    floatx4 bb = *(const floatx4*)(x + (size_t)t * 8 + 4);
    union { bf16x8 v; int4v i; } u;
#pragma unroll
    for (int q = 0; q < 4; q++) { u.v[q] = (__bf16)a[q]; u.v[q + 4] = (__bf16)bb[q]; }
    *(int4v*)(xb + (size_t)t * 8) = u.i;
  } else if (b < PREP_NX + PREP_NT1 + PREP_NT2) {
    // 64x64 tile transpose: w[K][128] -> wt[128][K], fp32 -> bf16
    bool is1 = b < PREP_NX + PREP_NT1;
    int tb = is1 ? (b - PREP_NX) : (b - PREP_NX - PREP_NT1);
    const int K = is1 ? FIN : 384;
    const float* w = is1 ? w1 : w2;
    __bf16* wt = is1 ? w1t : w2t;
    int tilesK = K >> 6;           // tiles along K
    int i = tb / (tilesK * 2);     // which of the 3 weight slices
    int rr = tb - i * tilesK * 2;
    int kt = rr >> 1;              // K-tile
    int nt = rr & 1;               // n-tile (128/64)
    const float* wS = w + (size_t)i * K * 128;
    __bf16* wtS = wt + (size_t)i * 128 * K;
    int k0 = kt * 64, n0 = nt * 64;
    __shared__ float tile[64][65];
    int tc = tid & 63, tr = tid >> 6;
#pragma unroll
    for (int q = 0; q < 16; q += 4) {
      int row = tr + (q + 0) * 4;  // unrolled 4-at-a-time below
      tile[row][tc] = wS[(size_t)(k0 + row) * 128 + n0 + tc];
      row = tr + (q + 1) * 4;
      tile[row][tc] = wS[(size_t)(k0 + row) * 128 + n0 + tc];
      row = tr + (q + 2) * 4;
      tile[row][tc] = wS[(size_t)(k0 + row) * 128 + n0 + tc];
      row = tr + (q + 3) * 4;
      tile[row][tc] = wS[(size_t)(k0 + row) * 128 + n0 + tc];
    }
    __syncthreads();
#pragma unroll
    for (int q = 0; q < 16; q++) {
      int nr = tr + q * 4;         // output row = n
      wtS[(size_t)(n0 + nr) * K + k0 + tc] = (__bf16)tile[tc][nr];
    }
  } else {
    int c = tid;
    if (c < NCLS) {
      float s = bfv[c];
      for (int k = 0; k < 384; k++) s += b2[k] * wf[k * NCLS + c];
      cc[c] = s;
    }
  }
}

// ---------------- parallel scan: per-block sums ----------------
__global__ __launch_bounds__(256) void k_scan_block(const int* __restrict__ cnt,
                                                    int* __restrict__ bsum) {
  int t = blockIdx.x * 256 + threadIdx.x;
  int v = (t < N_NODES) ? cnt[t] : 0;
#pragma unroll
  for (int o = 32; o >= 1; o >>= 1) v += __shfl_down(v, o);
  __shared__ int ws[4];
  if ((threadIdx.x & 63) == 0) ws[threadIdx.x >> 6] = v;
  __syncthreads();
  if (threadIdx.x == 0) bsum[blockIdx.x] = ws[0] + ws[1] + ws[2] + ws[3];
}

// ---------------- scan fill (inlines top-level scan of bsum) ----------------
__global__ __launch_bounds__(256) void k_scan_fill(const int* __restrict__ cnt,
                                                   const int* __restrict__ bsum,
                                                   int* __restrict__ rowptr) {
  int tid = threadIdx.x;
  int lane = tid & 63;
  int pv = (tid < blockIdx.x && tid < SCAN_NB) ? bsum[tid] : 0;
#pragma unroll
  for (int o = 32; o >= 1; o >>= 1) pv += __shfl_down(pv, o);
  __shared__ int ps[4];
  if (lane == 0) ps[tid >> 6] = pv;
  int t = blockIdx.x * 256 + tid;
  int c = (t < N_NODES) ? cnt[t] : 0;
  int v = c;
#pragma unroll
  for (int o = 1; o < 64; o <<= 1) {
    int n = __shfl_up(v, o);
    if (lane >= o) v += n;
  }
  __shared__ int wt[4];
  if (lane == 63) wt[tid >> 6] = v;
  __syncthreads();
  int add = ps[0] + ps[1] + ps[2] + ps[3];
  for (int w = 0; w < (tid >> 6); w++) add += wt[w];
  int ex = v - c + add;
  if (t < N_NODES) rowptr[t] = ex;
  if (t == 0) rowptr[N_NODES] = N_EDGES;
}

// ---------------- place edges (atomic-free: pos = rowptr[r] + rank[e]) -------
__global__ __launch_bounds__(256) void k_place(
    const int* __restrict__ idx, const float* __restrict__ vals,
    const int* __restrict__ rank, const int* __restrict__ rowptr,
    int2* __restrict__ epack) {
  int e = blockIdx.x * 256 + threadIdx.x;
  if (e < N_EDGES) {
    int r = idx[e];
    int c = idx[N_EDGES + e];
    int p = rowptr[r] + rank[e];
    epack[p] = make_int2(c, __float_as_int(vals[e]));
  }
}

// ---------------- SpMM 256-wide: both hop-1 chains; 4 gathers in flight ------
__global__ __launch_bounds__(256) void spmm256(
    const int* __restrict__ rowptr, const int2* __restrict__ epack,
    const __bf16* __restrict__ in,
    __bf16* __restrict__ out_lo, int slo,
    __bf16* __restrict__ out_hi, int shi) {
  int row = (int)((blockIdx.x * (size_t)blockDim.x + threadIdx.x) >> 6);
  if (row >= N_NODES) return;
  int lane = threadIdx.x & 63;
  int g = lane >> 5, l = lane & 31;
  int s = rowptr[row], e = rowptr[row + 1];
  float a[8] = {0.f, 0.f, 0.f, 0.f, 0.f, 0.f, 0.f, 0.f};
  int i = s + g;
  for (; i + 6 < e; i += 8) {
    int2 e0 = epack[i], e1 = epack[i + 2], e2 = epack[i + 4], e3 = epack[i + 6];
    bf16x8 p0 = *(const bf16x8*)(in + ((size_t)e0.x << 8) + 8 * l);
    bf16x8 p1 = *(const bf16x8*)(in + ((size_t)e1.x << 8) + 8 * l);
    bf16x8 p2 = *(const bf16x8*)(in + ((size_t)e2.x << 8) + 8 * l);
    bf16x8 p3 = *(const bf16x8*)(in + ((size_t)e3.x << 8) + 8 * l);
    float v0 = __int_as_float(e0.y), v1 = __int_as_float(e1.y);
    float v2 = __int_as_float(e2.y), v3 = __int_as_float(e3.y);
#pragma unroll
    for (int u = 0; u < 8; u++)
      a[u] += v0 * (float)p0[u] + v1 * (float)p1[u] + v2 * (float)p2[u] + v3 * (float)p3[u];
  }
  for (; i < e; i += 2) {
    int2 e0 = epack[i];
    bf16x8 p0 = *(const bf16x8*)(in + ((size_t)e0.x << 8) + 8 * l);
    float v0 = __int_as_float(e0.y);
#pragma unroll
    for (int u = 0; u < 8; u++) a[u] += v0 * (float)p0[u];
  }
#pragma unroll
  for (int u = 0; u < 8; u++) a[u] += __shfl_xor(a[u], 32);
  if (g == 0) {
    union { bf16x8 v; int4v i; } u8;
#pragma unroll
    for (int q = 0; q < 8; q++) u8.v[q] = (__bf16)a[q];
    if (l < 16) *(int4v*)(out_lo + (size_t)row * slo + 8 * l) = u8.i;
    else        *(int4v*)(out_hi + (size_t)row * shi + 8 * (l - 16)) = u8.i;
  }
}

// ---------------- SpMM 128-wide; 4 gathers in flight per group ---------------
__global__ __launch_bounds__(256) void spmm128(
    const int* __restrict__ rowptr, const int2* __restrict__ epack,
    const __bf16* __restrict__ in,
    __bf16* __restrict__ outp, int ostride) {
  int row = (int)((blockIdx.x * (size_t)blockDim.x + threadIdx.x) >> 6);
  if (row >= N_NODES) return;
  int lane = threadIdx.x & 63;
  int g = lane >> 4, l = lane & 15;
  int s = rowptr[row], e = rowptr[row + 1];
  float a[8] = {0.f, 0.f, 0.f, 0.f, 0.f, 0.f, 0.f, 0.f};
  int i = s + g;
  for (; i + 12 < e; i += 16) {
    int2 e0 = epack[i], e1 = epack[i + 4], e2 = epack[i + 8], e3 = epack[i + 12];
    bf16x8 p0 = *(const bf16x8*)(in + ((size_t)e0.x << 7) + 8 * l);
    bf16x8 p1 = *(const bf16x8*)(in + ((size_t)e1.x << 7) + 8 * l);
    bf16x8 p2 = *(const bf16x8*)(in + ((size_t)e2.x << 7) + 8 * l);
    bf16x8 p3 = *(const bf16x8*)(in + ((size_t)e3.x << 7) + 8 * l);
    float v0 = __int_as_float(e0.y), v1 = __int_as_float(e1.y);
    float v2 = __int_as_float(e2.y), v3 = __int_as_float(e3.y);
#pragma unroll
    for (int u = 0; u < 8; u++)
      a[u] += v0 * (float)p0[u] + v1 * (float)p1[u] + v2 * (float)p2[u] + v3 * (float)p3[u];
  }
  for (; i < e; i += 4) {
    int2 e0 = epack[i];
    bf16x8 p0 = *(const bf16x8*)(in + ((size_t)e0.x << 7) + 8 * l);
    float v0 = __int_as_float(e0.y);
#pragma unroll
    for (int u = 0; u < 8; u++) a[u] += v0 * (float)p0[u];
  }
#pragma unroll
  for (int u = 0; u < 8; u++) {
    a[u] += __shfl_xor(a[u], 16);
    a[u] += __shfl_xor(a[u], 32);
  }
  if (g == 0) {
    union { bf16x8 v; int4v i; } u8;
#pragma unroll
    for (int q = 0; q < 8; q++) u8.v[q] = (__bf16)a[q];
    *(int4v*)(outp + (size_t)row * ostride + 8 * l) = u8.i;
  }
}

// ---------------- MFMA bf16 GEMM, 128x128 tile, glds staging, 2-way LDS ------
template <bool HASB>
__global__ __launch_bounds__(256) void gemm_mfma(
    const __bf16* __restrict__ Ab, int M, int K,
    const __bf16* __restrict__ Bt,
    const float* __restrict__ bias,
    __bf16* __restrict__ out0, int s0,
    __bf16* __restrict__ out1, int s1,
    __bf16* __restrict__ out2, int s2) {
  __shared__ __align__(16) __bf16 sA[128 * 32];
  __shared__ __align__(16) __bf16 sB[128 * 32];
  int tid = threadIdx.x;
  int m0 = blockIdx.x * 128;
  int blk = blockIdx.y;
  const __bf16* Bblk = Bt + (size_t)blk * 128 * K;
  int wave = tid >> 6, lane = tid & 63;
  int wm = (wave & 1) * 64, wn = (wave >> 1) * 64;
  floatx4 acc[4][4] = {};

  int rA = lane >> 2;
  int gch = (lane & 3) ^ ((lane >> 3) & 3);
  int r0 = wave * 32 + rA;
  int r1 = r0 + 16;
  int gm0 = m0 + r0; gm0 = (gm0 < M) ? gm0 : (M - 1);
  int gm1 = m0 + r1; gm1 = (gm1 < M) ? gm1 : (M - 1);
  const __bf16* pa0 = Ab + (size_t)gm0 * K + gch * 8;
  const __bf16* pa1 = Ab + (size_t)gm1 * K + gch * 8;
  const __bf16* pb0 = Bblk + (size_t)r0 * K + gch * 8;
  const __bf16* pb1 = Bblk + (size_t)r1 * K + gch * 8;
  __bf16* lA0 = sA + wave * 1024;
  __bf16* lA1 = sA + wave * 1024 + 512;
  __bf16* lB0 = sB + wave * 1024;
  __bf16* lB1 = sB + wave * 1024 + 512;

  int fm = lane & 15, fg = lane >> 4;
  int sloto = (fg ^ ((fm >> 1) & 3)) * 8;

  for (int k0 = 0; k0 < K; k0 += 32) {
    __syncthreads();
    glds16(pa0 + k0, lA0);
    glds16(pa1 + k0, lA1);
    glds16(pb0 + k0, lB0);
    glds16(pb1 + k0, lB1);
    __syncthreads();

    bf16x8 af[4], bfr[4];
#pragma unroll
    for (int mt = 0; mt < 4; mt++)
      af[mt] = *(const bf16x8*)(sA + (wm + mt * 16 + fm) * 32 + sloto);
#pragma unroll
    for (int nt = 0; nt < 4; nt++)
      bfr[nt] = *(const bf16x8*)(sB + (wn + nt * 16 + fm) * 32 + sloto);
#pragma unroll
    for (int mt = 0; mt < 4; mt++)
#pragma unroll
      for (int nt = 0; nt < 4; nt++)
        acc[mt][nt] = __builtin_amdgcn_mfma_f32_16x16x32_bf16(af[mt], bfr[nt], acc[mt][nt], 0, 0, 0);
  }

  int colb = lane & 15, rbase = (lane >> 4) << 2;
  const float* bp = HASB ? (bias + blk * 128) : nullptr;
  __bf16* o = (blk == 0) ? out0 : ((blk == 1) ? out1 : out2);
  int os = (blk == 0) ? s0 : ((blk == 1) ? s1 : s2);
#pragma unroll
  for (int mt = 0; mt < 4; mt++)
#pragma unroll
    for (int r = 0; r < 4; r++) {
      int gm = m0 + wm + mt * 16 + rbase + r;
      if (gm >= M) continue;
#pragma unroll
      for (int nt = 0; nt < 4; nt++) {
        int gc = wn + nt * 16 + colb;
        float vv = acc[mt][nt][r];
        if (HASB) { vv += bp[gc]; vv = fmaxf(vv, 0.f); }
        o[(size_t)gm * os + gc] = (__bf16)vv;
      }
    }
}

// ---------------- final: logits = concat(f0,f1,f2) @ wf + constc; log_softmax
__global__ __launch_bounds__(256) void k_final(
    const __bf16* __restrict__ f0, const __bf16* __restrict__ f1,
    const __bf16* __restrict__ f2, const float* __restrict__ wf,
    const float* __restrict__ constc, float* __restrict__ out) {
  __shared__ __align__(16) float swf[NCLS * 388];  // [c][k], padded
  int tid = threadIdx.x;
  for (int i = tid; i < 384 * NCLS; i += 256) {
    int k = i >> 4, c = i & 15;
    swf[c * 388 + k] = wf[i];
  }
  __syncthreads();
  int r = blockIdx.x * 16 + (tid >> 4);
  int c = tid & 15;
  if (r >= N_NODES) return;
  float l = constc[c];
  const bf16x8* q0 = (const bf16x8*)(f0 + (size_t)r * HW_);
  const bf16x8* q1 = (const bf16x8*)(f1 + (size_t)r * HW_);
  const bf16x8* q2 = (const bf16x8*)(f2 + (size_t)r * HW_);
  const float* wrow = swf + c * 388;
#pragma unroll 4
  for (int kk = 0; kk < 16; kk++) {
    bf16x8 a = q0[kk];
#pragma unroll
    for (int u = 0; u < 8; u++) l += (float)a[u] * wrow[kk * 8 + u];
  }
#pragma unroll 4
  for (int kk = 0; kk < 16; kk++) {
    bf16x8 a = q1[kk];
#pragma unroll
    for (int u = 0; u < 8; u++) l += (float)a[u] * wrow[128 + kk * 8 + u];
  }
#pragma unroll 4
  for (int kk = 0; kk < 16; kk++) {
    bf16x8 a = q2[kk];
#pragma unroll
    for (int u = 0; u < 8; u++) l += (float)a[u] * wrow[256 + kk * 8 + u];
  }
  float m = l;
  for (int o = 8; o >= 1; o >>= 1) m = fmaxf(m, __shfl_xor(m, o, 16));
  float s = expf(l - m);
  for (int o = 8; o >= 1; o >>= 1) s += __shfl_xor(s, o, 16);
  out[(size_t)r * NCLS + c] = (l - m) - logf(s);
}

// ---------------- launch ----------------
extern "C" void kernel_launch(void* const* d_in, const int* in_sizes, int n_in,
                              void* d_out, int out_size, void* d_ws, size_t ws_size,
                              hipStream_t stream) {
  const float* x   = (const float*)d_in[0];
  const int*   adj = (const int*)d_in[1];
  const float* av  = (const float*)d_in[2];
  const float* w1  = (const float*)d_in[3];
  const float* b1  = (const float*)d_in[4];
  const float* w2  = (const float*)d_in[5];
  const float* b2  = (const float*)d_in[6];
  const float* wf  = (const float*)d_in[7];
  const float* bf  = (const float*)d_in[8];
  float* out = (float*)d_out;

  char* ws = (char*)d_ws;
  size_t off = 0;
  auto alloc = [&](size_t bytes) -> void* {
    off = (off + 255) & ~(size_t)255;
    void* p = ws + off;
    off += bytes;
    return p;
  };

  // xb (51.2 MB) dead after GEMM1 -> alias F0/F1/F2 (bf16, 12.8 MB each) on it.
  __bf16* xb  = (__bf16*)alloc((size_t)N_NODES * FIN * 2);
  __bf16* F0  = xb;
  __bf16* F1  = xb + (size_t)N_NODES * HW_;
  __bf16* F2  = xb + (size_t)2 * N_NODES * HW_;
  __bf16* a1b = (__bf16*)alloc((size_t)N_NODES * 384 * 2);
  __bf16* ABb = (__bf16*)alloc((size_t)N_NODES * 256 * 2);
  __bf16* Tb  = (__bf16*)alloc((size_t)N_NODES * HW_ * 2);
  __bf16* w1t = (__bf16*)alloc((size_t)3 * 128 * FIN * 2);
  __bf16* w2t = (__bf16*)alloc((size_t)3 * 128 * 384 * 2);
  int* rowptr = (int*)alloc((size_t)(N_NODES + 1) * 4);
  int* cnt    = (int*)alloc((size_t)N_NODES * 4);
  int* bsum   = (int*)alloc((size_t)SCAN_NB * 4);
  int* rankv  = (int*)alloc((size_t)N_EDGES * 4);
  int2* epack = (int2*)alloc((size_t)N_EDGES * 8);
  float* cc   = (float*)alloc(64);

  // CSR build: memset, rank(hist), scan_block, scan_fill, place (atomic-free)
  hipMemsetAsync(cnt, 0, (size_t)N_NODES * 4, stream);
  k_rank<<<(N_EDGES + 1023) / 1024, 256, 0, stream>>>(adj, cnt, rankv);
  k_prep<<<PREP_NX + PREP_NT1 + PREP_NT2 + 1, 256, 0, stream>>>(
      x, xb, w1, w1t, w2, w2t, b2, wf, bf, cc);
  k_scan_block<<<SCAN_NB, 256, 0, stream>>>(cnt, bsum);
  k_scan_fill<<<SCAN_NB, 256, 0, stream>>>(cnt, bsum, rowptr);
  k_place<<<(N_EDGES + 255) / 256, 256, 0, stream>>>(adj, av, rankv, rowptr, epack);

  dim3 g1((N_NODES + 127) / 128, 3);
  int spmm_grid = (N_NODES + 3) / 4;

  // GEMM1: relu(x@w1+b1): blk0 -> a1 cols 0-127; blk1 -> ABb lo; blk2 -> ABb hi
  gemm_mfma<true><<<g1, 256, 0, stream>>>(
      xb, N_NODES, FIN, w1t, b1, a1b, 384, ABb, 256, ABb + 128, 256);
  spmm256<<<spmm_grid, 256, 0, stream>>>(rowptr, epack, ABb, a1b + 128, 384, Tb, HW_);
  spmm128<<<spmm_grid, 256, 0, stream>>>(rowptr, epack, Tb, a1b + 256, 384);

  // GEMM2: a1@w2 (bias folded into constc): blk0 -> F0; blk1|blk2 -> ABb
  gemm_mfma<false><<<g1, 256, 0, stream>>>(
      a1b, N_NODES, 384, w2t, nullptr, F0, HW_, ABb, 256, ABb + 128, 256);
  spmm256<<<spmm_grid, 256, 0, stream>>>(rowptr, epack, ABb, F1, HW_, Tb, HW_);
  spmm128<<<spmm_grid, 256, 0, stream>>>(rowptr, epack, Tb, F2, HW_);

  // final fused GEMM + log_softmax
  k_final<<<(N_NODES + 15) / 16, 256, 0, stream>>>(F0, F1, F2, wf, cc, out);
}

// Round 8
// 358.203 us; speedup vs baseline: 1.6501x; 1.4727x over previous
//
#include <hip/hip_runtime.h>
#include <hip/hip_bf16.h>
#include <cstdint>
#include <cstddef>

#define N_NODES 50000
#define N_EDGES 800000
#define FIN 512
#define HW_ 128
#define NCLS 16
#define SCAN_NB 196  // ceil(50000/256)

typedef __attribute__((ext_vector_type(4))) float floatx4;
typedef __attribute__((ext_vector_type(4))) int int4v;
typedef __bf16 bf16x8 __attribute__((ext_vector_type(8)));

__device__ __forceinline__ void glds16(const __bf16* g, __bf16* l) {
  __builtin_amdgcn_global_load_lds(
      (const __attribute__((address_space(1))) void*)g,
      (__attribute__((address_space(3))) void*)l, 16, 0, 0);
}

// ---------------- rank: hist + per-edge rank (coalesced write) ----------------
__global__ __launch_bounds__(256) void k_rank(const int* __restrict__ idx,
                                              int* __restrict__ cnt,
                                              int* __restrict__ rank) {
  int e = blockIdx.x * 1024 + threadIdx.x;
#pragma unroll
  for (int u = 0; u < 4; u++) {
    int ee = e + u * 256;
    if (ee < N_EDGES) rank[ee] = atomicAdd(&cnt[idx[ee]], 1);
  }
}

// ------- prep: xcast | LDS-tiled w1 transpose | U = w2_blk@wf | constc -------
// Ut[80][384] bf16: Ut[16p+c][128j+r] = U_{(p-j) j}[r][c] (0 if p-j not in 0..2)
#define PREP_NX 12500          // 50000*512/8 / 256
#define PREP_NT1 48            // 3 * (512/64) * (128/64)
#define PREP_NU 120            // 80*384 / 256
__global__ __launch_bounds__(256) void k_prep(
    const float* __restrict__ x, __bf16* __restrict__ xb,
    const float* __restrict__ w1, __bf16* __restrict__ w1t,
    const float* __restrict__ w2, const float* __restrict__ wf,
    __bf16* __restrict__ Ut,
    const float* __restrict__ b2, const float* __restrict__ bfv,
    float* __restrict__ cc) {
  int b = blockIdx.x;
  int tid = threadIdx.x;
  if (b < PREP_NX) {
    int t = b * 256 + tid;
    floatx4 a = *(const floatx4*)(x + (size_t)t * 8);
    floatx4 bb = *(const floatx4*)(x + (size_t)t * 8 + 4);
    union { bf16x8 v; int4v i; } u;
#pragma unroll
    for (int q = 0; q < 4; q++) { u.v[q] = (__bf16)a[q]; u.v[q + 4] = (__bf16)bb[q]; }
    *(int4v*)(xb + (size_t)t * 8) = u.i;
  } else if (b < PREP_NX + PREP_NT1) {
    // 64x64 tile transpose: w1[K][128] -> w1t[128][K], fp32 -> bf16
    int tb = b - PREP_NX;
    const int K = FIN;
    int tilesK = K >> 6;
    int i = tb / (tilesK * 2);
    int rr = tb - i * tilesK * 2;
    int kt = rr >> 1;
    int nt = rr & 1;
    const float* wS = w1 + (size_t)i * K * 128;
    __bf16* wtS = w1t + (size_t)i * 128 * K;
    int k0 = kt * 64, n0 = nt * 64;
    __shared__ float tile[64][65];
    int tc = tid & 63, tr = tid >> 6;
#pragma unroll
    for (int q = 0; q < 16; q++) {
      int row = tr + q * 4;
      tile[row][tc] = wS[(size_t)(k0 + row) * 128 + n0 + tc];
    }
    __syncthreads();
#pragma unroll
    for (int q = 0; q < 16; q++) {
      int nr = tr + q * 4;
      wtS[(size_t)(n0 + nr) * K + k0 + tc] = (__bf16)tile[tc][nr];
    }
  } else if (b < PREP_NX + PREP_NT1 + PREP_NU) {
    int t = (b - PREP_NX - PREP_NT1) * 256 + tid;  // [0, 30720)
    int col = t / 384;            // 0..79 = 16p + c
    int q = t - col * 384;        // 0..383 = 128j + r
    int p = col >> 4, c = col & 15;
    int j = q >> 7;
    int i = p - j;
    float val = 0.f;
    if (i >= 0 && i <= 2) {
      const float* w2row = w2 + ((size_t)i * 384 + q) * 128;  // w2[i][q][.]
      const float* wfcol = wf + (size_t)128 * i * NCLS + c;
      for (int m = 0; m < 128; m++) val += w2row[m] * wfcol[m * NCLS];
    }
    Ut[(size_t)col * 384 + q] = (__bf16)val;
  } else {
    int c = tid;
    if (c < NCLS) {
      float s = bfv[c];
      for (int k = 0; k < 384; k++) s += b2[k] * wf[k * NCLS + c];
      cc[c] = s;
    }
  }
}

// ---------------- parallel scan: per-block sums ----------------
__global__ __launch_bounds__(256) void k_scan_block(const int* __restrict__ cnt,
                                                    int* __restrict__ bsum) {
  int t = blockIdx.x * 256 + threadIdx.x;
  int v = (t < N_NODES) ? cnt[t] : 0;
#pragma unroll
  for (int o = 32; o >= 1; o >>= 1) v += __shfl_down(v, o);
  __shared__ int ws[4];
  if ((threadIdx.x & 63) == 0) ws[threadIdx.x >> 6] = v;
  __syncthreads();
  if (threadIdx.x == 0) bsum[blockIdx.x] = ws[0] + ws[1] + ws[2] + ws[3];
}

// ---------------- scan fill (inlines top-level scan of bsum) ----------------
__global__ __launch_bounds__(256) void k_scan_fill(const int* __restrict__ cnt,
                                                   const int* __restrict__ bsum,
                                                   int* __restrict__ rowptr) {
  int tid = threadIdx.x;
  int lane = tid & 63;
  int pv = (tid < blockIdx.x && tid < SCAN_NB) ? bsum[tid] : 0;
#pragma unroll
  for (int o = 32; o >= 1; o >>= 1) pv += __shfl_down(pv, o);
  __shared__ int ps[4];
  if (lane == 0) ps[tid >> 6] = pv;
  int t = blockIdx.x * 256 + tid;
  int c = (t < N_NODES) ? cnt[t] : 0;
  int v = c;
#pragma unroll
  for (int o = 1; o < 64; o <<= 1) {
    int n = __shfl_up(v, o);
    if (lane >= o) v += n;
  }
  __shared__ int wt[4];
  if (lane == 63) wt[tid >> 6] = v;
  __syncthreads();
  int add = ps[0] + ps[1] + ps[2] + ps[3];
  for (int w = 0; w < (tid >> 6); w++) add += wt[w];
  int ex = v - c + add;
  if (t < N_NODES) rowptr[t] = ex;
  if (t == 0) rowptr[N_NODES] = N_EDGES;
}

// ---------------- place edges (atomic-free: pos = rowptr[r] + rank[e]) -------
__global__ __launch_bounds__(256) void k_place(
    const int* __restrict__ idx, const float* __restrict__ vals,
    const int* __restrict__ rank, const int* __restrict__ rowptr,
    int2* __restrict__ epack) {
  int e = blockIdx.x * 256 + threadIdx.x;
  if (e < N_EDGES) {
    int r = idx[e];
    int c = idx[N_EDGES + e];
    int p = rowptr[r] + rank[e];
    epack[p] = make_int2(c, __float_as_int(vals[e]));
  }
}

// ---------------- GEMM1: hb = relu(xb @ w1 + b1), MFMA, glds staging ---------
__global__ __launch_bounds__(256) void gemm1(
    const __bf16* __restrict__ Ab,
    const __bf16* __restrict__ Bt,      // w1t [3][128][512]
    const float* __restrict__ bias,     // [384]
    __bf16* __restrict__ hb) {          // [N,384]
  const int M = N_NODES, K = FIN;
  __shared__ __align__(16) __bf16 sA[128 * 32];
  __shared__ __align__(16) __bf16 sB[128 * 32];
  int tid = threadIdx.x;
  int m0 = blockIdx.x * 128;
  int blk = blockIdx.y;
  const __bf16* Bblk = Bt + (size_t)blk * 128 * K;
  int wave = tid >> 6, lane = tid & 63;
  int wm = (wave & 1) * 64, wn = (wave >> 1) * 64;
  floatx4 acc[4][4] = {};

  int rA = lane >> 2;
  int gch = (lane & 3) ^ ((lane >> 3) & 3);
  int r0 = wave * 32 + rA;
  int r1 = r0 + 16;
  int gm0 = m0 + r0; gm0 = (gm0 < M) ? gm0 : (M - 1);
  int gm1 = m0 + r1; gm1 = (gm1 < M) ? gm1 : (M - 1);
  const __bf16* pa0 = Ab + (size_t)gm0 * K + gch * 8;
  const __bf16* pa1 = Ab + (size_t)gm1 * K + gch * 8;
  const __bf16* pb0 = Bblk + (size_t)r0 * K + gch * 8;
  const __bf16* pb1 = Bblk + (size_t)r1 * K + gch * 8;
  __bf16* lA0 = sA + wave * 1024;
  __bf16* lA1 = sA + wave * 1024 + 512;
  __bf16* lB0 = sB + wave * 1024;
  __bf16* lB1 = sB + wave * 1024 + 512;

  int fm = lane & 15, fg = lane >> 4;
  int sloto = (fg ^ ((fm >> 1) & 3)) * 8;

  for (int k0 = 0; k0 < K; k0 += 32) {
    __syncthreads();
    glds16(pa0 + k0, lA0);
    glds16(pa1 + k0, lA1);
    glds16(pb0 + k0, lB0);
    glds16(pb1 + k0, lB1);
    __syncthreads();

    bf16x8 af[4], bfr[4];
#pragma unroll
    for (int mt = 0; mt < 4; mt++)
      af[mt] = *(const bf16x8*)(sA + (wm + mt * 16 + fm) * 32 + sloto);
#pragma unroll
    for (int nt = 0; nt < 4; nt++)
      bfr[nt] = *(const bf16x8*)(sB + (wn + nt * 16 + fm) * 32 + sloto);
#pragma unroll
    for (int mt = 0; mt < 4; mt++)
#pragma unroll
      for (int nt = 0; nt < 4; nt++)
        acc[mt][nt] = __builtin_amdgcn_mfma_f32_16x16x32_bf16(af[mt], bfr[nt], acc[mt][nt], 0, 0, 0);
  }

  int colb = lane & 15, rbase = (lane >> 4) << 2;
#pragma unroll
  for (int mt = 0; mt < 4; mt++)
#pragma unroll
    for (int r = 0; r < 4; r++) {
      int gm = m0 + wm + mt * 16 + rbase + r;
      if (gm >= M) continue;
#pragma unroll
      for (int nt = 0; nt < 4; nt++) {
        int gc = blk * 128 + wn + nt * 16 + colb;
        float vv = acc[mt][nt][r] + bias[gc];
        vv = fmaxf(vv, 0.f);
        hb[(size_t)gm * 384 + gc] = (__bf16)vv;
      }
    }
}

// -------- S-GEMM: S[N,64] = hb@Ublk cols 0-63 (p=0..3); R4 = cols 64-79 ------
// No LDS: B (Ut, 61 KB) is L2-resident; A-fragments straight from global.
__global__ __launch_bounds__(256) void k_sgemm(
    const __bf16* __restrict__ hb,   // [N,384]
    const __bf16* __restrict__ Ut,   // [80,384]
    float* __restrict__ S,           // [N,64]  (p = 0..3)
    float* __restrict__ R4) {        // [N,16]  (p = 4)
  const int M = N_NODES;
  int wave = threadIdx.x >> 6, lane = threadIdx.x & 63;
  int fm = lane & 15, fg = lane >> 4;
  int m0 = blockIdx.x * 128 + wave * 32;
  floatx4 acc[2][5] = {};
  int r0 = m0 + fm;      r0 = (r0 < M) ? r0 : (M - 1);
  int r1 = m0 + 16 + fm; r1 = (r1 < M) ? r1 : (M - 1);
  const __bf16* pa0 = hb + (size_t)r0 * 384 + fg * 8;
  const __bf16* pa1 = hb + (size_t)r1 * 384 + fg * 8;
  const __bf16* pb = Ut + (size_t)fm * 384 + fg * 8;
#pragma unroll 2
  for (int k0 = 0; k0 < 384; k0 += 32) {
    bf16x8 a0 = *(const bf16x8*)(pa0 + k0);
    bf16x8 a1 = *(const bf16x8*)(pa1 + k0);
#pragma unroll
    for (int nt = 0; nt < 5; nt++) {
      bf16x8 bv = *(const bf16x8*)(pb + (size_t)nt * 16 * 384 + k0);
      acc[0][nt] = __builtin_amdgcn_mfma_f32_16x16x32_bf16(a0, bv, acc[0][nt], 0, 0, 0);
      acc[1][nt] = __builtin_amdgcn_mfma_f32_16x16x32_bf16(a1, bv, acc[1][nt], 0, 0, 0);
    }
  }
  int colb = lane & 15, rbase = (lane >> 4) << 2;
#pragma unroll
  for (int mt = 0; mt < 2; mt++)
#pragma unroll
    for (int r = 0; r < 4; r++) {
      int gm = m0 + mt * 16 + rbase + r;
      if (gm >= M) continue;
#pragma unroll
      for (int nt = 0; nt < 4; nt++)
        S[(size_t)gm * 64 + nt * 16 + colb] = acc[mt][nt][r];
      R4[(size_t)gm * 16 + colb] = acc[mt][4][r];
    }
}

// ---- Horner hop: Rout = A@Rin + S_p (16-wide fp32); FINAL adds const+lsm ----
template <bool FINAL>
__global__ __launch_bounds__(256) void k_hop(
    const int* __restrict__ rowptr, const int2* __restrict__ epack,
    const float* __restrict__ Rin,      // [N,16]
    const float* __restrict__ S, int sofs,  // S + row*64 + sofs
    float* __restrict__ Rout,           // [N,16] (or out)
    const float* __restrict__ cc) {
  int tid = threadIdx.x;
  int grp = tid >> 4, l = tid & 15;
  int row = blockIdx.x * 16 + grp;
  if (row >= N_NODES) return;
  int s = rowptr[row], e = rowptr[row + 1];
  float a = S[(size_t)row * 64 + sofs + l];
  for (int i = s; i < e; i += 16) {
    int take = e - i; if (take > 16) take = 16;
    int2 ed = (l < take) ? epack[i + l] : make_int2(0, 0);
    int j = 0;
    for (; j + 4 <= take; j += 4) {
      int c0 = __shfl(ed.x, j, 16), c1 = __shfl(ed.x, j + 1, 16);
      int c2 = __shfl(ed.x, j + 2, 16), c3 = __shfl(ed.x, j + 3, 16);
      float v0 = __int_as_float(__shfl(ed.y, j, 16));
      float v1 = __int_as_float(__shfl(ed.y, j + 1, 16));
      float v2 = __int_as_float(__shfl(ed.y, j + 2, 16));
      float v3 = __int_as_float(__shfl(ed.y, j + 3, 16));
      float g0 = Rin[(size_t)c0 * 16 + l];
      float g1 = Rin[(size_t)c1 * 16 + l];
      float g2 = Rin[(size_t)c2 * 16 + l];
      float g3 = Rin[(size_t)c3 * 16 + l];
      a += v0 * g0 + v1 * g1 + v2 * g2 + v3 * g3;
    }
    for (; j < take; j++) {
      int c0 = __shfl(ed.x, j, 16);
      float v0 = __int_as_float(__shfl(ed.y, j, 16));
      a += v0 * Rin[(size_t)c0 * 16 + l];
    }
  }
  if (!FINAL) {
    Rout[(size_t)row * 16 + l] = a;
  } else {
    a += cc[l];
    float m = a;
#pragma unroll
    for (int o = 8; o >= 1; o >>= 1) m = fmaxf(m, __shfl_xor(m, o, 16));
    float sm = expf(a - m);
#pragma unroll
    for (int o = 8; o >= 1; o >>= 1) sm += __shfl_xor(sm, o, 16);
    Rout[(size_t)row * 16 + l] = (a - m) - logf(sm);
  }
}

// ---------------- launch ----------------
extern "C" void kernel_launch(void* const* d_in, const int* in_sizes, int n_in,
                              void* d_out, int out_size, void* d_ws, size_t ws_size,
                              hipStream_t stream) {
  const float* x   = (const float*)d_in[0];
  const int*   adj = (const int*)d_in[1];
  const float* av  = (const float*)d_in[2];
  const float* w1  = (const float*)d_in[3];
  const float* b1  = (const float*)d_in[4];
  const float* w2  = (const float*)d_in[5];
  const float* b2  = (const float*)d_in[6];
  const float* wf  = (const float*)d_in[7];
  const float* bf  = (const float*)d_in[8];
  float* out = (float*)d_out;

  char* ws = (char*)d_ws;
  size_t off = 0;
  auto alloc = [&](size_t bytes) -> void* {
    off = (off + 255) & ~(size_t)255;
    void* p = ws + off;
    off += bytes;
    return p;
  };

  // xb (51.2 MB) dead after gemm1 -> alias S, R4, RA, RB (22.4 MB) onto it.
  __bf16* xb  = (__bf16*)alloc((size_t)N_NODES * FIN * 2);
  float* S    = (float*)xb;                                    // [N,64]
  float* R4   = (float*)((char*)xb + (size_t)N_NODES * 64 * 4);
  float* RA   = (float*)((char*)R4 + (size_t)N_NODES * 16 * 4);
  float* RB   = (float*)((char*)RA + (size_t)N_NODES * 16 * 4);
  __bf16* hb  = (__bf16*)alloc((size_t)N_NODES * 384 * 2);
  __bf16* w1t = (__bf16*)alloc((size_t)3 * 128 * FIN * 2);
  __bf16* Ut  = (__bf16*)alloc((size_t)80 * 384 * 2);
  int* rowptr = (int*)alloc((size_t)(N_NODES + 1) * 4);
  int* cnt    = (int*)alloc((size_t)N_NODES * 4);
  int* bsum   = (int*)alloc((size_t)SCAN_NB * 4);
  int* rankv  = (int*)alloc((size_t)N_EDGES * 4);
  int2* epack = (int2*)alloc((size_t)N_EDGES * 8);
  float* cc   = (float*)alloc(64);

  // CSR build (atomic-free placement) + prep
  hipMemsetAsync(cnt, 0, (size_t)N_NODES * 4, stream);
  k_rank<<<(N_EDGES + 1023) / 1024, 256, 0, stream>>>(adj, cnt, rankv);
  k_prep<<<PREP_NX + PREP_NT1 + PREP_NU + 1, 256, 0, stream>>>(
      x, xb, w1, w1t, w2, wf, Ut, b2, bf, cc);
  k_scan_block<<<SCAN_NB, 256, 0, stream>>>(cnt, bsum);
  k_scan_fill<<<SCAN_NB, 256, 0, stream>>>(cnt, bsum, rowptr);
  k_place<<<(N_EDGES + 255) / 256, 256, 0, stream>>>(adj, av, rankv, rowptr, epack);

  // GEMM1: hb = relu(x@w1 + b1)  [N,384] bf16
  dim3 g1((N_NODES + 127) / 128, 3);
  gemm1<<<g1, 256, 0, stream>>>(xb, w1t, b1, hb);

  // S-GEMM: S[N,64] (p=0..3) + R4[N,16] (p=4)
  k_sgemm<<<(N_NODES + 127) / 128, 256, 0, stream>>>(hb, Ut, S, R4);

  // Horner: R = S_p + A*R, p = 3,2,1,0 (last fused with +const and log_softmax)
  int hop_grid = (N_NODES + 15) / 16;
  k_hop<false><<<hop_grid, 256, 0, stream>>>(rowptr, epack, R4, S, 48, RB, cc);
  k_hop<false><<<hop_grid, 256, 0, stream>>>(rowptr, epack, RB, S, 32, RA, cc);
  k_hop<false><<<hop_grid, 256, 0, stream>>>(rowptr, epack, RA, S, 16, RB, cc);
  k_hop<true><<<hop_grid, 256, 0, stream>>>(rowptr, epack, RB, S, 0, out, cc);
}